// Round 1
// baseline (3113.239 us; speedup 1.0000x reference)
//
#include <hip/hip_runtime.h>
#include <math.h>

// ---------------------------------------------------------------------------
// SFMCNN: 3 branches, each: RBF-conv -> topk triangle-CReLU -> alpha-pool (x2)
// then RBF-conv -> CReLU -> concat -> FC.
// All fp32 (reference arithmetic d2 = |p|^2 + |w|^2 - 2 p.w; discontinuous
// top-k threshold makes low precision risky).
// ---------------------------------------------------------------------------

#define NB 16   // batch
#define NBR 3   // branches

// ---------------- |w|^2 per filter row ----------------
__global__ __launch_bounds__(256) void sw2_kernel(
    const float* __restrict__ w1, const float* __restrict__ w2,
    const float* __restrict__ w3,
    float* __restrict__ s1, float* __restrict__ s2, float* __restrict__ s3) {
  int t = blockIdx.x * blockDim.x + threadIdx.x;
  if (t < 192) {                       // 3*64 rows of 25
    const float* r = w1 + t * 25;
    float s = 0.f;
    for (int i = 0; i < 25; i++) s += r[i] * r[i];
    s1[t] = s;
  } else if (t < 192 + 384) {          // 3*128 rows of 576
    int u = t - 192;
    const float* r = w2 + u * 576;
    float s = 0.f;
    for (int i = 0; i < 576; i++) s += r[i] * r[i];
    s2[u] = s;
  } else if (t < 192 + 384 + 768) {    // 3*256 rows of 1152
    int u = t - 576;
    const float* r = w3 + u * 1152;
    float s = 0.f;
    for (int i = 0; i < 1152; i++) s += r[i] * r[i];
    s3[u] = s;
  }
}

// ---------------- Layer 1: 1ch 5x5 pad2 -> 64ch, crelu(k=32), pool ----------
// block = 64 threads (one per out channel); one block = 2x2 output group.
__global__ __launch_bounds__(64) void layer1_kernel(
    const float* __restrict__ x,    // [16][3][96][96]
    const float* __restrict__ w1,   // [3][64][25]
    const float* __restrict__ sw2,  // [3][64]
    const float* __restrict__ tri,  // [3][3]
    float* __restrict__ a1)         // [3][16][48][48][64]
{
  const int gidx = blockIdx.x;             // 0..2303
  const int gy = gidx / 48, gx = gidx % 48;
  const int n = blockIdx.y, br = blockIdx.z;
  const int o = threadIdx.x;               // channel

  __shared__ float win[6][8];
  __shared__ __align__(16) float dls[64][4];
  __shared__ float sp2s[4];
  __shared__ float thrs[4];

  const int y0 = gy * 2 - 2, x0 = gx * 2 - 2;
  const float* xb = x + ((size_t)(n * 3 + br)) * 96 * 96;
  for (int idx = o; idx < 36; idx += 64) {
    int wy = idx / 6, wx = idx % 6;
    int y = y0 + wy, xx = x0 + wx;
    float v = 0.f;
    if (y >= 0 && y < 96 && xx >= 0 && xx < 96) v = xb[y * 96 + xx];
    win[wy][wx] = v;
  }
  __syncthreads();

  if (o < 4) {
    int py = o >> 1, px = o & 1;
    float s = 0.f;
    for (int ky = 0; ky < 5; ky++)
      for (int kx = 0; kx < 5; kx++) {
        float v = win[py + ky][px + kx];
        s += v * v;
      }
    sp2s[o] = s;
  }

  const float* wr = w1 + (br * 64 + o) * 25;
  float acc0 = 0.f, acc1 = 0.f, acc2 = 0.f, acc3 = 0.f;
  for (int ky = 0; ky < 5; ky++) {
    for (int kx = 0; kx < 5; kx++) {
      float wv = wr[ky * 5 + kx];
      acc0 += wv * win[0 + ky][0 + kx];
      acc1 += wv * win[0 + ky][1 + kx];
      acc2 += wv * win[1 + ky][0 + kx];
      acc3 += wv * win[1 + ky][1 + kx];
    }
  }
  __syncthreads();  // sp2s visible

  float sw = sw2[br * 64 + o];
  float d[4];
  float acc[4] = {acc0, acc1, acc2, acc3};
  for (int p = 0; p < 4; p++) {
    float d2 = sp2s[p] + sw - 2.f * acc[p];
    d[p] = sqrtf(fmaxf(d2, 1e-12f));
    dls[o][p] = d[p];
  }
  __syncthreads();

  int c0 = 0, c1 = 0, c2 = 0, c3 = 0;
  for (int j = 0; j < 64; j++) {
    float4 xj = *reinterpret_cast<const float4*>(&dls[j][0]);
    c0 += (xj.x > d[0]) || (xj.x == d[0] && j < o);
    c1 += (xj.y > d[1]) || (xj.y == d[1] && j < o);
    c2 += (xj.z > d[2]) || (xj.z == d[2] && j < o);
    c3 += (xj.w > d[3]) || (xj.w == d[3] && j < o);
  }
  if (c0 == 31) thrs[0] = d[0];
  if (c1 == 31) thrs[1] = d[1];
  if (c2 == 31) thrs[2] = d[2];
  if (c3 == 31) thrs[3] = d[3];
  __syncthreads();

  const float w = tri[br * 3 + 0];
  const float alpha[4] = {0.9f, 0.93f, 0.96f, 0.99f};
  float pooled = 0.f;
  for (int p = 0; p < 4; p++) {
    float th = fminf(thrs[p], w);
    float dd = (d[p] > th) ? w : d[p];
    float act = 1.f - dd / w;
    pooled += act * alpha[p];
  }
  pooled *= 0.25f;
  a1[((((size_t)(br * 16 + n)) * 48 + gy) * 48 + gx) * 64 + o] = pooled;
}

// ---------------- Layers 2/3: CIN-ch 3x3 pad1 -> COUT, crelu, opt pool ------
template <int CIN, int COUT, int HIN, int KRANK, int POOL, int LIDX>
__global__ __launch_bounds__(COUT) void rbf3_kernel(
    const float* __restrict__ in,   // [3][16][HIN][HIN][CIN]
    const float* __restrict__ w,    // [3][COUT][CIN*9]
    const float* __restrict__ sw2,  // [3][COUT]
    const float* __restrict__ tri,  // [3][3]
    float* __restrict__ out)        // pool: [3][16][HIN/2][HIN/2][COUT]
                                    // else: [3][16][HIN][HIN][COUT]
{
  const int GW = HIN / 2;
  const int gidx = blockIdx.x;
  const int gy = gidx / GW, gx = gidx % GW;
  const int n = blockIdx.y, br = blockIdx.z;
  const int o = threadIdx.x;

  __shared__ __align__(16) float win[CIN][20];  // [c][wy*4+wx], pad to 20
  __shared__ __align__(16) float dls[COUT][4];
  __shared__ float colsum[16];
  __shared__ float thrs[4];

  const float* ib = in + ((size_t)(br * 16 + n)) * HIN * HIN * CIN;
  const int y0 = gy * 2 - 1, x0 = gx * 2 - 1;
  for (int idx = o; idx < CIN * 16; idx += COUT) {
    int c = idx % CIN;
    int pos = idx / CIN;
    int wy = pos >> 2, wx = pos & 3;
    int y = y0 + wy, xx = x0 + wx;
    float v = 0.f;
    if (y >= 0 && y < HIN && xx >= 0 && xx < HIN) v = ib[(y * HIN + xx) * CIN + c];
    win[c][pos] = v;
  }
  __syncthreads();

  if (o < 16) {
    float s = 0.f;
    for (int c = 0; c < CIN; c++) {
      float v = win[c][o];
      s += v * v;
    }
    colsum[o] = s;
  }

  const float* wr = w + ((size_t)(br * COUT + o)) * CIN * 9;
  float acc0 = 0.f, acc1 = 0.f, acc2 = 0.f, acc3 = 0.f;
  for (int c = 0; c < CIN; c++) {
    float4 r0 = *reinterpret_cast<const float4*>(&win[c][0]);
    float4 r1 = *reinterpret_cast<const float4*>(&win[c][4]);
    float4 r2 = *reinterpret_cast<const float4*>(&win[c][8]);
    float4 r3 = *reinterpret_cast<const float4*>(&win[c][12]);
    const float* wc = wr + c * 9;
    float w0 = wc[0], w1 = wc[1], w2 = wc[2];
    acc0 += w0 * r0.x + w1 * r0.y + w2 * r0.z;
    acc1 += w0 * r0.y + w1 * r0.z + w2 * r0.w;
    acc2 += w0 * r1.x + w1 * r1.y + w2 * r1.z;
    acc3 += w0 * r1.y + w1 * r1.z + w2 * r1.w;
    w0 = wc[3]; w1 = wc[4]; w2 = wc[5];
    acc0 += w0 * r1.x + w1 * r1.y + w2 * r1.z;
    acc1 += w0 * r1.y + w1 * r1.z + w2 * r1.w;
    acc2 += w0 * r2.x + w1 * r2.y + w2 * r2.z;
    acc3 += w0 * r2.y + w1 * r2.z + w2 * r2.w;
    w0 = wc[6]; w1 = wc[7]; w2 = wc[8];
    acc0 += w0 * r2.x + w1 * r2.y + w2 * r2.z;
    acc1 += w0 * r2.y + w1 * r2.z + w2 * r2.w;
    acc2 += w0 * r3.x + w1 * r3.y + w2 * r3.z;
    acc3 += w0 * r3.y + w1 * r3.z + w2 * r3.w;
  }
  __syncthreads();  // colsum visible

  float sp2[4];
  for (int p = 0; p < 4; p++) {
    int py = p >> 1, px = p & 1;
    float s = 0.f;
    for (int ky = 0; ky < 3; ky++)
      for (int kx = 0; kx < 3; kx++) s += colsum[(py + ky) * 4 + (px + kx)];
    sp2[p] = s;
  }
  float sw = sw2[br * COUT + o];
  float acc[4] = {acc0, acc1, acc2, acc3};
  float d[4];
  for (int p = 0; p < 4; p++) {
    float d2 = sp2[p] + sw - 2.f * acc[p];
    d[p] = sqrtf(fmaxf(d2, 1e-12f));
    dls[o][p] = d[p];
  }
  __syncthreads();

  int c0 = 0, c1 = 0, c2 = 0, c3 = 0;
  for (int j = 0; j < COUT; j++) {
    float4 xj = *reinterpret_cast<const float4*>(&dls[j][0]);
    c0 += (xj.x > d[0]) || (xj.x == d[0] && j < o);
    c1 += (xj.y > d[1]) || (xj.y == d[1] && j < o);
    c2 += (xj.z > d[2]) || (xj.z == d[2] && j < o);
    c3 += (xj.w > d[3]) || (xj.w == d[3] && j < o);
  }
  if (c0 == KRANK) thrs[0] = d[0];
  if (c1 == KRANK) thrs[1] = d[1];
  if (c2 == KRANK) thrs[2] = d[2];
  if (c3 == KRANK) thrs[3] = d[3];
  __syncthreads();

  const float w_ = tri[br * 3 + LIDX];
  float act[4];
  for (int p = 0; p < 4; p++) {
    float th = fminf(thrs[p], w_);
    float dd = (d[p] > th) ? w_ : d[p];
    act[p] = 1.f - dd / w_;
  }

  if (POOL) {
    const float alpha[4] = {0.9f, 0.93f, 0.96f, 0.99f};
    float pooled =
        0.25f * (act[0] * alpha[0] + act[1] * alpha[1] + act[2] * alpha[2] +
                 act[3] * alpha[3]);
    out[((((size_t)(br * 16 + n)) * GW + gy) * GW + gx) * COUT + o] = pooled;
  } else {
    for (int p = 0; p < 4; p++) {
      int py = p >> 1, px = p & 1;
      out[((((size_t)(br * 16 + n)) * HIN + (gy * 2 + py)) * HIN +
           (gx * 2 + px)) * COUT + o] = act[p];
    }
  }
}

// ---------------- FC: out[n][o] = feats . fc_w[o] + fc_b[o] -----------------
// feats layout [3][16][24][24][256]; fc index = br*147456 + c*576 + (y*24+x)
__global__ __launch_bounds__(256) void fc_kernel(
    const float* __restrict__ feats, const float* __restrict__ fcw,
    const float* __restrict__ fcb, float* __restrict__ outp) {
  const int oo = blockIdx.x;  // 0..9
  const int n = blockIdx.y;   // 0..15
  const int t = threadIdx.x;
  const float* wrow = fcw + (size_t)oo * 442368;
  float s = 0.f;
  for (int i = t; i < 442368; i += 256) {
    int br = i / 147456;
    int r = i - br * 147456;
    int c = r / 576;
    int pth = r - c * 576;  // y*24+x
    float fv = feats[(((size_t)(br * 16 + n)) * 576 + pth) * 256 + c];
    s += wrow[i] * fv;
  }
  __shared__ float red[256];
  red[t] = s;
  __syncthreads();
  for (int st = 128; st > 0; st >>= 1) {
    if (t < st) red[t] += red[t + st];
    __syncthreads();
  }
  if (t == 0) outp[n * 10 + oo] = red[0] + fcb[oo];
}

// ---------------------------------------------------------------------------
extern "C" void kernel_launch(void* const* d_in, const int* in_sizes, int n_in,
                              void* d_out, int out_size, void* d_ws,
                              size_t ws_size, hipStream_t stream) {
  const float* x   = (const float*)d_in[0];
  const float* w1  = (const float*)d_in[1];
  const float* w2  = (const float*)d_in[2];
  const float* w3  = (const float*)d_in[3];
  const float* tri = (const float*)d_in[4];
  const float* fcw = (const float*)d_in[5];
  const float* fcb = (const float*)d_in[6];
  float* out = (float*)d_out;

  float* ws = (float*)d_ws;
  float* a1    = ws;                  // 3*16*48*48*64 = 7,077,888
  float* a2    = a1 + 7077888;        // 3*16*24*24*128 = 3,538,944
  float* feats = a2 + 3538944;        // 3*16*24*24*256 = 7,077,888
  float* s1    = feats + 7077888;     // 192
  float* s2    = s1 + 192;            // 384
  float* s3    = s2 + 384;            // 768

  sw2_kernel<<<dim3(6), dim3(256), 0, stream>>>(w1, w2, w3, s1, s2, s3);
  layer1_kernel<<<dim3(2304, 16, 3), dim3(64), 0, stream>>>(x, w1, s1, tri, a1);
  rbf3_kernel<64, 128, 48, 63, 1, 1>
      <<<dim3(576, 16, 3), dim3(128), 0, stream>>>(a1, w2, s2, tri, a2);
  rbf3_kernel<128, 256, 24, 152, 0, 2>
      <<<dim3(144, 16, 3), dim3(256), 0, stream>>>(a2, w3, s3, tri, feats);
  fc_kernel<<<dim3(10, 16), dim3(256), 0, stream>>>(feats, fcw, fcb, out);
}

// Round 2
// 1077.560 us; speedup vs baseline: 2.8892x; 2.8892x over previous
//
#include <hip/hip_runtime.h>
#include <math.h>

// ---------------------------------------------------------------------------
// SFMCNN fp32: 3 branches of (RBF-conv -> topk triangle-CReLU -> alpha-pool)x2
// -> RBF-conv -> CReLU -> FC.
// R1: transposed weights (coalesced), 2x4-position blocks, coalesced FC.
// ---------------------------------------------------------------------------

// ---------------- |w|^2 per filter row (original layouts) ----------------
__global__ __launch_bounds__(256) void sw2_kernel(
    const float* __restrict__ w1, const float* __restrict__ w2,
    const float* __restrict__ w3,
    float* __restrict__ s1, float* __restrict__ s2, float* __restrict__ s3) {
  int t = blockIdx.x * blockDim.x + threadIdx.x;
  if (t < 192) {
    const float* r = w1 + t * 25;
    float s = 0.f;
    for (int i = 0; i < 25; i++) s += r[i] * r[i];
    s1[t] = s;
  } else if (t < 192 + 384) {
    int u = t - 192;
    const float* r = w2 + u * 576;
    float s = 0.f;
    for (int i = 0; i < 576; i++) s += r[i] * r[i];
    s2[u] = s;
  } else if (t < 192 + 384 + 768) {
    int u = t - 576;
    const float* r = w3 + u * 1152;
    float s = 0.f;
    for (int i = 0; i < 1152; i++) s += r[i] * r[i];
    s3[u] = s;
  }
}

// ---------------- transpose conv weights: out[br][k][o] = in[br][o][k] -----
__global__ __launch_bounds__(256) void tr_w_kernel(
    const float* __restrict__ in, float* __restrict__ out, int O, int K) {
  int idx = blockIdx.x * blockDim.x + threadIdx.x;
  int total = 3 * O * K;
  if (idx >= total) return;
  int o = idx % O;
  int r = idx / O;
  int k = r % K;
  int br = r / K;
  out[((size_t)br * K + k) * O + o] = in[((size_t)br * O + o) * K + k];
}

// ---------------- transpose fc_w: [oo][br][c][pth] -> [oo][br][pth][c] -----
// per (oo,br): src[c][pth] (c<256, pth<576) -> dst[pth][c]. 32x32 LDS tiles.
__global__ __launch_bounds__(256) void tr_fcw_kernel(
    const float* __restrict__ fcw, float* __restrict__ fcwt) {
  int tb = blockIdx.x;           // 18 pth-tiles x 8 c-tiles
  int pt = tb % 18, ct = tb / 18;
  int ob = blockIdx.y;           // oo*3+br
  __shared__ float tile[32][33];
  const float* src = fcw + (size_t)ob * 147456;
  float* dst = fcwt + (size_t)ob * 147456;
  int tx = threadIdx.x, ty = threadIdx.y;  // (32,8)
  int pth0 = pt * 32, c0 = ct * 32;
  for (int i = 0; i < 32; i += 8) {
    int c = c0 + ty + i;
    tile[ty + i][tx] = src[(size_t)c * 576 + pth0 + tx];
  }
  __syncthreads();
  for (int i = 0; i < 32; i += 8) {
    int pth = pth0 + ty + i;
    dst[(size_t)pth * 256 + c0 + tx] = tile[tx][ty + i];
  }
}

// ---------------- Layer 1: 1ch 5x5 pad2 -> 64ch, crelu(rank31), pool -------
// block = 64 threads (one per out channel); covers 2 rows x 4 cols of conv
// pixels = 2 pool outputs.
__global__ __launch_bounds__(64) void layer1_kernel(
    const float* __restrict__ x,    // [16][3][96][96]
    const float* __restrict__ w1t,  // [3][25][64]
    const float* __restrict__ sw2,  // [3][64]
    const float* __restrict__ tri,  // [3][3]
    float* __restrict__ a1)         // [3][16][48][48][64]
{
  const int gidx = blockIdx.x;           // 48 pool-rows x 24 col-pairs
  const int gy = gidx / 24, gx = gidx % 24;
  const int n = blockIdx.y, br = blockIdx.z;
  const int o = threadIdx.x;

  __shared__ __align__(16) float win[6][8];
  __shared__ __align__(16) float dls[64][8];
  __shared__ float sp2s[8];
  __shared__ float thrs[8];

  const int y0 = gy * 2 - 2, x0 = gx * 4 - 2;
  const float* xb = x + ((size_t)(n * 3 + br)) * 96 * 96;
  if (o < 48) {
    int wy = o >> 3, wx = o & 7;
    int y = y0 + wy, xx = x0 + wx;
    float v = 0.f;
    if (y >= 0 && y < 96 && xx >= 0 && xx < 96) v = xb[y * 96 + xx];
    win[wy][wx] = v;
  }
  __syncthreads();

  if (o < 8) {
    int py = o >> 2, px = o & 3;
    float s = 0.f;
#pragma unroll
    for (int ky = 0; ky < 5; ky++)
#pragma unroll
      for (int kx = 0; kx < 5; kx++) {
        float v = win[py + ky][px + kx];
        s += v * v;
      }
    sp2s[o] = s;
  }

  const float* wb = w1t + br * 25 * 64 + o;
  float wv[25];
#pragma unroll
  for (int j = 0; j < 25; j++) wv[j] = wb[j * 64];

  float acc[2][4] = {};
#pragma unroll
  for (int wy = 0; wy < 6; wy++) {
    float4 ra = *reinterpret_cast<const float4*>(&win[wy][0]);
    float4 rb = *reinterpret_cast<const float4*>(&win[wy][4]);
    float r[8] = {ra.x, ra.y, ra.z, ra.w, rb.x, rb.y, rb.z, rb.w};
#pragma unroll
    for (int py = 0; py < 2; py++) {
      int ky = wy - py;
      if (ky < 0 || ky > 4) continue;
#pragma unroll
      for (int kx = 0; kx < 5; kx++) {
        float wvv = wv[ky * 5 + kx];
#pragma unroll
        for (int px = 0; px < 4; px++) acc[py][px] += wvv * r[px + kx];
      }
    }
  }
  __syncthreads();  // sp2s visible

  float sw = sw2[br * 64 + o];
  float d[8];
#pragma unroll
  for (int p = 0; p < 8; p++) {
    float d2 = sp2s[p] + sw - 2.f * acc[p >> 2][p & 3];
    d[p] = sqrtf(fmaxf(d2, 1e-12f));
  }
  *reinterpret_cast<float4*>(&dls[o][0]) = make_float4(d[0], d[1], d[2], d[3]);
  *reinterpret_cast<float4*>(&dls[o][4]) = make_float4(d[4], d[5], d[6], d[7]);
  __syncthreads();

  int cnt[8] = {};
  const float4* dl4 = reinterpret_cast<const float4*>(dls);
  for (int j = 0; j < 64; j++) {
    float4 e0 = dl4[2 * j], e1 = dl4[2 * j + 1];
    bool tl = j < o;
    cnt[0] += (e0.x > d[0]) || (e0.x == d[0] && tl);
    cnt[1] += (e0.y > d[1]) || (e0.y == d[1] && tl);
    cnt[2] += (e0.z > d[2]) || (e0.z == d[2] && tl);
    cnt[3] += (e0.w > d[3]) || (e0.w == d[3] && tl);
    cnt[4] += (e1.x > d[4]) || (e1.x == d[4] && tl);
    cnt[5] += (e1.y > d[5]) || (e1.y == d[5] && tl);
    cnt[6] += (e1.z > d[6]) || (e1.z == d[6] && tl);
    cnt[7] += (e1.w > d[7]) || (e1.w == d[7] && tl);
  }
#pragma unroll
  for (int p = 0; p < 8; p++)
    if (cnt[p] == 31) thrs[p] = d[p];
  __syncthreads();

  const float w = tri[br * 3 + 0];
  const float A2[2][2] = {{0.9f, 0.93f}, {0.96f, 0.99f}};
#pragma unroll
  for (int g = 0; g < 2; g++) {
    float pooled = 0.f;
#pragma unroll
    for (int py = 0; py < 2; py++)
#pragma unroll
      for (int q = 0; q < 2; q++) {
        int p = py * 4 + g * 2 + q;
        float th = fminf(thrs[p], w);
        float dd = (d[p] > th) ? w : d[p];
        pooled += (1.f - dd / w) * A2[py][q];
      }
    pooled *= 0.25f;
    a1[((((size_t)(br * 16 + n)) * 48 + gy) * 48 + (gx * 2 + g)) * 64 + o] =
        pooled;
  }
}

// ---------------- Layers 2/3: 3x3 pad1 RBF conv, crelu, opt pool ----------
// block = COUT threads, covers 2 rows x 4 cols of conv outputs.
template <int CIN, int COUT, int HIN, int KRANK, int POOL, int LIDX>
__global__ __launch_bounds__(COUT) void rbf3_kernel(
    const float* __restrict__ in,   // [3][16][HIN][HIN][CIN]
    const float* __restrict__ wt,   // [3][CIN*9][COUT]
    const float* __restrict__ sw2,  // [3][COUT]
    const float* __restrict__ tri,  // [3][3]
    float* __restrict__ out)
{
  const int GX = HIN / 4;
  const int gidx = blockIdx.x;
  const int gy = gidx / GX, gx = gidx % GX;
  const int n = blockIdx.y, br = blockIdx.z;
  const int o = threadIdx.x;

  __shared__ __align__(16) float win[CIN][4][8];  // rows 4, cols 6 used
  __shared__ __align__(16) float dls[COUT][8];
  __shared__ float colsum[24];
  __shared__ float thrs[8];

  const float* ib = in + ((size_t)(br * 16 + n)) * HIN * HIN * CIN;
  const int y0 = gy * 2 - 1, x0 = gx * 4 - 1;
  for (int idx = o; idx < CIN * 24; idx += COUT) {
    int c = idx % CIN;
    int pos = idx / CIN;          // 0..23
    int wy = pos / 6, wx = pos % 6;
    int y = y0 + wy, xx = x0 + wx;
    float v = 0.f;
    if (y >= 0 && y < HIN && xx >= 0 && xx < HIN)
      v = ib[(y * HIN + xx) * CIN + c];
    win[c][wy][wx] = v;
  }
  __syncthreads();

  if (o < 24) {
    int wy = o / 6, wx = o % 6;
    float s = 0.f;
    for (int c = 0; c < CIN; c++) {
      float v = win[c][wy][wx];
      s += v * v;
    }
    colsum[o] = s;
  }

  const float* wtb = wt + (size_t)br * CIN * 9 * COUT + o;
  float acc[2][4] = {};
  for (int c = 0; c < CIN; c++) {
    float4 q0 = *reinterpret_cast<const float4*>(&win[c][0][0]);
    float2 h0 = *reinterpret_cast<const float2*>(&win[c][0][4]);
    float4 q1 = *reinterpret_cast<const float4*>(&win[c][1][0]);
    float2 h1 = *reinterpret_cast<const float2*>(&win[c][1][4]);
    float4 q2 = *reinterpret_cast<const float4*>(&win[c][2][0]);
    float2 h2 = *reinterpret_cast<const float2*>(&win[c][2][4]);
    float4 q3 = *reinterpret_cast<const float4*>(&win[c][3][0]);
    float2 h3 = *reinterpret_cast<const float2*>(&win[c][3][4]);
    float rr[4][6] = {{q0.x, q0.y, q0.z, q0.w, h0.x, h0.y},
                      {q1.x, q1.y, q1.z, q1.w, h1.x, h1.y},
                      {q2.x, q2.y, q2.z, q2.w, h2.x, h2.y},
                      {q3.x, q3.y, q3.z, q3.w, h3.x, h3.y}};
    const float* wc = wtb + (size_t)c * 9 * COUT;
    float wv[9];
#pragma unroll
    for (int j = 0; j < 9; j++) wv[j] = wc[j * COUT];
#pragma unroll
    for (int ky = 0; ky < 3; ky++)
#pragma unroll
      for (int kx = 0; kx < 3; kx++) {
        float wvv = wv[ky * 3 + kx];
#pragma unroll
        for (int py = 0; py < 2; py++)
#pragma unroll
          for (int px = 0; px < 4; px++)
            acc[py][px] += wvv * rr[py + ky][px + kx];
      }
  }
  __syncthreads();  // colsum visible

  float sw = sw2[br * COUT + o];
  float d[8];
#pragma unroll
  for (int p = 0; p < 8; p++) {
    int py = p >> 2, px = p & 3;
    float s = 0.f;
#pragma unroll
    for (int ky = 0; ky < 3; ky++)
#pragma unroll
      for (int kx = 0; kx < 3; kx++) s += colsum[(py + ky) * 6 + (px + kx)];
    float d2 = s + sw - 2.f * acc[py][px];
    d[p] = sqrtf(fmaxf(d2, 1e-12f));
  }
  *reinterpret_cast<float4*>(&dls[o][0]) = make_float4(d[0], d[1], d[2], d[3]);
  *reinterpret_cast<float4*>(&dls[o][4]) = make_float4(d[4], d[5], d[6], d[7]);
  __syncthreads();

  int cnt[8] = {};
  const float4* dl4 = reinterpret_cast<const float4*>(dls);
  for (int j = 0; j < COUT; j++) {
    float4 e0 = dl4[2 * j], e1 = dl4[2 * j + 1];
    bool tl = j < o;
    cnt[0] += (e0.x > d[0]) || (e0.x == d[0] && tl);
    cnt[1] += (e0.y > d[1]) || (e0.y == d[1] && tl);
    cnt[2] += (e0.z > d[2]) || (e0.z == d[2] && tl);
    cnt[3] += (e0.w > d[3]) || (e0.w == d[3] && tl);
    cnt[4] += (e1.x > d[4]) || (e1.x == d[4] && tl);
    cnt[5] += (e1.y > d[5]) || (e1.y == d[5] && tl);
    cnt[6] += (e1.z > d[6]) || (e1.z == d[6] && tl);
    cnt[7] += (e1.w > d[7]) || (e1.w == d[7] && tl);
  }
#pragma unroll
  for (int p = 0; p < 8; p++)
    if (cnt[p] == KRANK) thrs[p] = d[p];
  __syncthreads();

  const float w_ = tri[br * 3 + LIDX];
  float act[8];
#pragma unroll
  for (int p = 0; p < 8; p++) {
    float th = fminf(thrs[p], w_);
    float dd = (d[p] > th) ? w_ : d[p];
    act[p] = 1.f - dd / w_;
  }

  if (POOL) {
    const float A2[2][2] = {{0.9f, 0.93f}, {0.96f, 0.99f}};
    const int GW = HIN / 2;
#pragma unroll
    for (int g = 0; g < 2; g++) {
      float pooled = 0.f;
#pragma unroll
      for (int py = 0; py < 2; py++)
#pragma unroll
        for (int q = 0; q < 2; q++)
          pooled += act[py * 4 + g * 2 + q] * A2[py][q];
      pooled *= 0.25f;
      out[((((size_t)(br * 16 + n)) * GW + gy) * GW + (gx * 2 + g)) * COUT +
          o] = pooled;
    }
  } else {
#pragma unroll
    for (int p = 0; p < 8; p++) {
      int oy = gy * 2 + (p >> 2), ox = gx * 4 + (p & 3);
      out[((((size_t)(br * 16 + n)) * HIN + oy) * HIN + ox) * COUT + o] =
          act[p];
    }
  }
}

// ---------------- FC: fully coalesced float4 on both streams --------------
// feats [3][16][576][256]; fcwt [oo][3][576][256]
__global__ __launch_bounds__(256) void fc_kernel(
    const float* __restrict__ feats, const float* __restrict__ fcwt,
    const float* __restrict__ fcb, float* __restrict__ outp) {
  const int oo = blockIdx.x;  // 0..9
  const int n = blockIdx.y;   // 0..15
  const int t = threadIdx.x;
  float s = 0.f;
  for (int br = 0; br < 3; br++) {
    const float4* fb = reinterpret_cast<const float4*>(
        feats + ((size_t)(br * 16 + n)) * 147456);
    const float4* wb = reinterpret_cast<const float4*>(
        fcwt + ((size_t)(oo * 3 + br)) * 147456);
    for (int i = t; i < 36864; i += 256) {
      float4 f = fb[i], w = wb[i];
      s += f.x * w.x + f.y * w.y + f.z * w.z + f.w * w.w;
    }
  }
  __shared__ float red[256];
  red[t] = s;
  __syncthreads();
  for (int st = 128; st > 0; st >>= 1) {
    if (t < st) red[t] += red[t + st];
    __syncthreads();
  }
  if (t == 0) outp[n * 10 + oo] = red[0] + fcb[oo];
}

// ---------------------------------------------------------------------------
extern "C" void kernel_launch(void* const* d_in, const int* in_sizes, int n_in,
                              void* d_out, int out_size, void* d_ws,
                              size_t ws_size, hipStream_t stream) {
  const float* x   = (const float*)d_in[0];
  const float* w1  = (const float*)d_in[1];
  const float* w2  = (const float*)d_in[2];
  const float* w3  = (const float*)d_in[3];
  const float* tri = (const float*)d_in[4];
  const float* fcw = (const float*)d_in[5];
  const float* fcb = (const float*)d_in[6];
  float* out = (float*)d_out;

  float* ws = (float*)d_ws;
  float* a1    = ws;                  // 7,077,888
  float* a2    = a1 + 7077888;        // 3,538,944
  float* feats = a2 + 3538944;        // 7,077,888
  float* s1    = feats + 7077888;     // 192
  float* s2    = s1 + 192;            // 384
  float* s3    = s2 + 384;            // 768
  float* w1t   = s3 + 768;            // 4,800
  float* w2t   = w1t + 4800;          // 221,184
  float* w3t   = w2t + 221184;        // 884,736
  float* fcwt  = a1;                  // aliases a1 (dead after layer2)

  tr_w_kernel<<<dim3((4800 + 255) / 256), dim3(256), 0, stream>>>(w1, w1t, 64, 25);
  tr_w_kernel<<<dim3((221184 + 255) / 256), dim3(256), 0, stream>>>(w2, w2t, 128, 576);
  tr_w_kernel<<<dim3((884736 + 255) / 256), dim3(256), 0, stream>>>(w3, w3t, 256, 1152);
  sw2_kernel<<<dim3(6), dim3(256), 0, stream>>>(w1, w2, w3, s1, s2, s3);

  layer1_kernel<<<dim3(1152, 16, 3), dim3(64), 0, stream>>>(x, w1t, s1, tri, a1);
  rbf3_kernel<64, 128, 48, 63, 1, 1>
      <<<dim3(288, 16, 3), dim3(128), 0, stream>>>(a1, w2t, s2, tri, a2);
  // a1 dead from here; reuse for transposed fc weights
  tr_fcw_kernel<<<dim3(144, 30), dim3(32, 8), 0, stream>>>(fcw, fcwt);
  rbf3_kernel<128, 256, 24, 152, 0, 2>
      <<<dim3(72, 16, 3), dim3(256), 0, stream>>>(a2, w3t, s3, tri, feats);
  fc_kernel<<<dim3(10, 16), dim3(256), 0, stream>>>(feats, fcwt, fcb, out);
}

// Round 3
// 837.160 us; speedup vs baseline: 3.7188x; 1.2872x over previous
//
#include <hip/hip_runtime.h>
#include <math.h>

// ---------------------------------------------------------------------------
// SFMCNN fp32. R2: wave-cooperative radix-select for the top-k threshold
// (kills the O(C^2) rank loop), 2x8 position blocking (144 FMA / 9 loads),
// reduced LDS store conflicts (stride-52 window rows).
// ---------------------------------------------------------------------------

// ---------------- |w|^2 per filter row ----------------
__global__ __launch_bounds__(256) void sw2_kernel(
    const float* __restrict__ w1, const float* __restrict__ w2,
    const float* __restrict__ w3,
    float* __restrict__ s1, float* __restrict__ s2, float* __restrict__ s3) {
  int t = blockIdx.x * blockDim.x + threadIdx.x;
  if (t < 192) {
    const float* r = w1 + t * 25;
    float s = 0.f;
    for (int i = 0; i < 25; i++) s += r[i] * r[i];
    s1[t] = s;
  } else if (t < 192 + 384) {
    int u = t - 192;
    const float* r = w2 + u * 576;
    float s = 0.f;
    for (int i = 0; i < 576; i++) s += r[i] * r[i];
    s2[u] = s;
  } else if (t < 192 + 384 + 768) {
    int u = t - 576;
    const float* r = w3 + u * 1152;
    float s = 0.f;
    for (int i = 0; i < 1152; i++) s += r[i] * r[i];
    s3[u] = s;
  }
}

// ---------------- transpose conv weights: out[br][k][o] = in[br][o][k] -----
__global__ __launch_bounds__(256) void tr_w_kernel(
    const float* __restrict__ in, float* __restrict__ out, int O, int K) {
  int idx = blockIdx.x * blockDim.x + threadIdx.x;
  int total = 3 * O * K;
  if (idx >= total) return;
  int o = idx % O;
  int r = idx / O;
  int k = r % K;
  int br = r / K;
  out[((size_t)br * K + k) * O + o] = in[((size_t)br * O + o) * K + k];
}

// ---------------- transpose fc_w: [oo][br][c][pth] -> [oo][br][pth][c] -----
__global__ __launch_bounds__(256) void tr_fcw_kernel(
    const float* __restrict__ fcw, float* __restrict__ fcwt) {
  int tb = blockIdx.x;           // 18 pth-tiles x 8 c-tiles
  int pt = tb % 18, ct = tb / 18;
  int ob = blockIdx.y;           // oo*3+br
  __shared__ float tile[32][33];
  const float* src = fcw + (size_t)ob * 147456;
  float* dst = fcwt + (size_t)ob * 147456;
  int tx = threadIdx.x, ty = threadIdx.y;  // (32,8)
  int pth0 = pt * 32, c0 = ct * 32;
  for (int i = 0; i < 32; i += 8) {
    int c = c0 + ty + i;
    tile[ty + i][tx] = src[(size_t)c * 576 + pth0 + tx];
  }
  __syncthreads();
  for (int i = 0; i < 32; i += 8) {
    int pth = pth0 + ty + i;
    dst[(size_t)pth * 256 + c0 + tx] = tile[tx][ty + i];
  }
}

// ---- wave radix-select: value with descending rank KRANK among C = R*64
// values in lds (uint bit pattern of positive floats; monotone order). ----
template <int R>
__device__ __forceinline__ float wave_kth(const unsigned int* v_lds, int lane,
                                          int krank) {
  unsigned int v[R];
#pragma unroll
  for (int r = 0; r < R; r++) v[r] = v_lds[r * 64 + lane];
  unsigned int prefix = 0;
  int rem = krank;
  for (int b = 30; b >= 0; --b) {
    unsigned int top = (prefix >> b) | 1u;
    int cnt = 0;
#pragma unroll
    for (int r = 0; r < R; r++)
      cnt += __popcll(__ballot((v[r] >> b) == top));
    if (cnt > rem) prefix |= (1u << b);
    else rem -= cnt;
  }
  return __uint_as_float(prefix);
}

// ---------------- Layer 1: 1ch 5x5 pad2 -> 64ch, crelu(rank31), pool -------
// block = 64 threads; covers 2 rows x 8 cols of conv pixels = 4 pool outputs.
__global__ __launch_bounds__(64) void layer1_kernel(
    const float* __restrict__ x,    // [16][3][96][96]
    const float* __restrict__ w1t,  // [3][25][64]
    const float* __restrict__ sw2,  // [3][64]
    const float* __restrict__ tri,  // [3][3]
    float* __restrict__ a1)         // [3][16][48][48][64]
{
  const int gidx = blockIdx.x;           // 48 pool-rows x 12 col-quads
  const int gy = gidx / 12, gx = gidx % 12;
  const int n = blockIdx.y, br = blockIdx.z;
  const int o = threadIdx.x;
  const int lane = o & 63;

  __shared__ __align__(16) float win[6][12];
  __shared__ float sp2s[16];
  __shared__ unsigned int dbits[16][64];
  __shared__ float thrs[16];

  const int y0 = gy * 2 - 2, x0 = gx * 8 - 2;
  const float* xb = x + ((size_t)(n * 3 + br)) * 96 * 96;
  for (int idx = o; idx < 72; idx += 64) {
    int wy = idx / 12, wx = idx % 12;
    int y = y0 + wy, xx = x0 + wx;
    float v = 0.f;
    if (y >= 0 && y < 96 && xx >= 0 && xx < 96) v = xb[y * 96 + xx];
    win[wy][wx] = v;
  }
  __syncthreads();

  if (o < 16) {
    int py = o >> 3, px = o & 7;
    float s = 0.f;
#pragma unroll
    for (int ky = 0; ky < 5; ky++)
#pragma unroll
      for (int kx = 0; kx < 5; kx++) {
        float v = win[py + ky][px + kx];
        s += v * v;
      }
    sp2s[o] = s;
  }

  const float* wb = w1t + br * 25 * 64 + o;
  float wv[25];
#pragma unroll
  for (int j = 0; j < 25; j++) wv[j] = wb[j * 64];

  float acc[2][8] = {};
#pragma unroll
  for (int wy = 0; wy < 6; wy++) {
    float4 ra = *reinterpret_cast<const float4*>(&win[wy][0]);
    float4 rb = *reinterpret_cast<const float4*>(&win[wy][4]);
    float4 rc = *reinterpret_cast<const float4*>(&win[wy][8]);
    float r[12] = {ra.x, ra.y, ra.z, ra.w, rb.x, rb.y,
                   rb.z, rb.w, rc.x, rc.y, rc.z, rc.w};
#pragma unroll
    for (int py = 0; py < 2; py++) {
      int ky = wy - py;
      if (ky < 0 || ky > 4) continue;
#pragma unroll
      for (int kx = 0; kx < 5; kx++) {
        float wvv = wv[ky * 5 + kx];
#pragma unroll
        for (int px = 0; px < 8; px++) acc[py][px] += wvv * r[px + kx];
      }
    }
  }
  __syncthreads();  // sp2s visible

  float sw = sw2[br * 64 + o];
  float d[16];
#pragma unroll
  for (int p = 0; p < 16; p++) {
    float d2 = sp2s[p] + sw - 2.f * acc[p >> 3][p & 7];
    d[p] = sqrtf(fmaxf(d2, 1e-12f));
    dbits[p][o] = __float_as_uint(d[p]);
  }
  __syncthreads();

  for (int p = 0; p < 16; p++) {
    float t = wave_kth<1>(&dbits[p][0], lane, 31);
    if (lane == 0) thrs[p] = t;
  }
  __syncthreads();

  const float w = tri[br * 3 + 0];
  const float A2[2][2] = {{0.9f, 0.93f}, {0.96f, 0.99f}};
#pragma unroll
  for (int g = 0; g < 4; g++) {
    float pooled = 0.f;
#pragma unroll
    for (int py = 0; py < 2; py++)
#pragma unroll
      for (int q = 0; q < 2; q++) {
        int p = py * 8 + g * 2 + q;
        float th = fminf(thrs[p], w);
        float dd = (d[p] > th) ? w : d[p];
        pooled += (1.f - dd / w) * A2[py][q];
      }
    pooled *= 0.25f;
    a1[((((size_t)(br * 16 + n)) * 48 + gy) * 48 + (gx * 4 + g)) * 64 + o] =
        pooled;
  }
}

// ---------------- Layers 2/3: 3x3 pad1 RBF conv, crelu, opt pool ----------
// block = COUT threads, covers 2 rows x 8 cols of conv outputs.
template <int CIN, int COUT, int HIN, int KRANK, int POOL, int LIDX>
__global__ __launch_bounds__(COUT) void rbf3_kernel(
    const float* __restrict__ in,   // [3][16][HIN][HIN][CIN]
    const float* __restrict__ wt,   // [3][CIN*9][COUT]
    const float* __restrict__ sw2,  // [3][COUT]
    const float* __restrict__ tri,  // [3][3]
    float* __restrict__ out)
{
  constexpr int NW = COUT / 64;
  const int GX = HIN / 8;
  const int gidx = blockIdx.x;
  const int gy = gidx / GX, gx = gidx % GX;
  const int n = blockIdx.y, br = blockIdx.z;
  const int o = threadIdx.x;
  const int lane = o & 63, wid = o >> 6;

  // win rows: stride 52 floats per c (8-bank spread on staging stores);
  // 4 rows of 12 (10 used). dbits aliases win (dead after conv).
  __shared__ __align__(16) float win[CIN * 52];
  __shared__ float colsum[40];
  __shared__ float thrs[16];
  unsigned int* dbits = reinterpret_cast<unsigned int*>(win);  // [16][COUT]

  const float* ib = in + ((size_t)(br * 16 + n)) * HIN * HIN * CIN;
  const int y0 = gy * 2 - 1, x0 = gx * 8 - 1;
  for (int idx = o; idx < CIN * 40; idx += COUT) {
    int c = idx % CIN;
    int pos = idx / CIN;          // 0..39
    int wy = pos / 10, wx = pos % 10;
    int y = y0 + wy, xx = x0 + wx;
    float v = 0.f;
    if (y >= 0 && y < HIN && xx >= 0 && xx < HIN)
      v = ib[(y * HIN + xx) * CIN + c];
    win[c * 52 + wy * 12 + wx] = v;
  }
  __syncthreads();

  if (o < 40) {
    int wy = o / 10, wx = o % 10;
    float s = 0.f;
    for (int c = 0; c < CIN; c++) {
      float v = win[c * 52 + wy * 12 + wx];
      s += v * v;
    }
    colsum[o] = s;
  }

  const float* wtb = wt + (size_t)br * CIN * 9 * COUT + o;
  float acc[2][8] = {};
  for (int c = 0; c < CIN; c++) {
    const float* wb = &win[c * 52];
    float r[4][12];
#pragma unroll
    for (int wy = 0; wy < 4; wy++) {
      float4 qa = *reinterpret_cast<const float4*>(wb + wy * 12);
      float4 qb = *reinterpret_cast<const float4*>(wb + wy * 12 + 4);
      float2 qc = *reinterpret_cast<const float2*>(wb + wy * 12 + 8);
      r[wy][0] = qa.x; r[wy][1] = qa.y; r[wy][2] = qa.z; r[wy][3] = qa.w;
      r[wy][4] = qb.x; r[wy][5] = qb.y; r[wy][6] = qb.z; r[wy][7] = qb.w;
      r[wy][8] = qc.x; r[wy][9] = qc.y;
    }
    const float* wc = wtb + (size_t)c * 9 * COUT;
    float wv[9];
#pragma unroll
    for (int j = 0; j < 9; j++) wv[j] = wc[j * COUT];
#pragma unroll
    for (int ky = 0; ky < 3; ky++)
#pragma unroll
      for (int kx = 0; kx < 3; kx++) {
        float wvv = wv[ky * 3 + kx];
#pragma unroll
        for (int py = 0; py < 2; py++)
#pragma unroll
          for (int px = 0; px < 8; px++)
            acc[py][px] += wvv * r[py + ky][px + kx];
      }
  }

  float sw = sw2[br * COUT + o];
  __syncthreads();  // all win reads done (alias!), colsum visible

  float d[16];
#pragma unroll
  for (int p = 0; p < 16; p++) {
    int py = p >> 3, px = p & 7;
    float s = 0.f;
#pragma unroll
    for (int ky = 0; ky < 3; ky++)
#pragma unroll
      for (int kx = 0; kx < 3; kx++) s += colsum[(py + ky) * 10 + (px + kx)];
    float d2 = s + sw - 2.f * acc[py][px];
    d[p] = sqrtf(fmaxf(d2, 1e-12f));
  }
#pragma unroll
  for (int p = 0; p < 16; p++) dbits[p * COUT + o] = __float_as_uint(d[p]);
  __syncthreads();

  for (int p = wid; p < 16; p += NW) {
    float t = wave_kth<NW>(&dbits[p * COUT], lane, KRANK);
    if (lane == 0) thrs[p] = t;
  }
  __syncthreads();

  const float w_ = tri[br * 3 + LIDX];
  float act[16];
#pragma unroll
  for (int p = 0; p < 16; p++) {
    float th = fminf(thrs[p], w_);
    float dd = (d[p] > th) ? w_ : d[p];
    act[p] = 1.f - dd / w_;
  }

  if (POOL) {
    const float A2[2][2] = {{0.9f, 0.93f}, {0.96f, 0.99f}};
    const int GW = HIN / 2;
#pragma unroll
    for (int g = 0; g < 4; g++) {
      float pooled = 0.f;
#pragma unroll
      for (int py = 0; py < 2; py++)
#pragma unroll
        for (int q = 0; q < 2; q++)
          pooled += act[py * 8 + g * 2 + q] * A2[py][q];
      pooled *= 0.25f;
      out[((((size_t)(br * 16 + n)) * GW + gy) * GW + (gx * 4 + g)) * COUT +
          o] = pooled;
    }
  } else {
#pragma unroll
    for (int p = 0; p < 16; p++) {
      int oy = gy * 2 + (p >> 3), ox = gx * 8 + (p & 7);
      out[((((size_t)(br * 16 + n)) * HIN + oy) * HIN + ox) * COUT + o] =
          act[p];
    }
  }
}

// ---------------- FC: fully coalesced float4 on both streams --------------
__global__ __launch_bounds__(256) void fc_kernel(
    const float* __restrict__ feats, const float* __restrict__ fcwt,
    const float* __restrict__ fcb, float* __restrict__ outp) {
  const int oo = blockIdx.x;  // 0..9
  const int n = blockIdx.y;   // 0..15
  const int t = threadIdx.x;
  float s = 0.f;
  for (int br = 0; br < 3; br++) {
    const float4* fb = reinterpret_cast<const float4*>(
        feats + ((size_t)(br * 16 + n)) * 147456);
    const float4* wb = reinterpret_cast<const float4*>(
        fcwt + ((size_t)(oo * 3 + br)) * 147456);
    for (int i = t; i < 36864; i += 256) {
      float4 f = fb[i], w = wb[i];
      s += f.x * w.x + f.y * w.y + f.z * w.z + f.w * w.w;
    }
  }
  __shared__ float red[256];
  red[t] = s;
  __syncthreads();
  for (int st = 128; st > 0; st >>= 1) {
    if (t < st) red[t] += red[t + st];
    __syncthreads();
  }
  if (t == 0) outp[n * 10 + oo] = red[0] + fcb[oo];
}

// ---------------------------------------------------------------------------
extern "C" void kernel_launch(void* const* d_in, const int* in_sizes, int n_in,
                              void* d_out, int out_size, void* d_ws,
                              size_t ws_size, hipStream_t stream) {
  const float* x   = (const float*)d_in[0];
  const float* w1  = (const float*)d_in[1];
  const float* w2  = (const float*)d_in[2];
  const float* w3  = (const float*)d_in[3];
  const float* tri = (const float*)d_in[4];
  const float* fcw = (const float*)d_in[5];
  const float* fcb = (const float*)d_in[6];
  float* out = (float*)d_out;

  float* ws = (float*)d_ws;
  float* a1    = ws;                  // 7,077,888
  float* a2    = a1 + 7077888;        // 3,538,944
  float* feats = a2 + 3538944;        // 7,077,888
  float* s1    = feats + 7077888;     // 192
  float* s2    = s1 + 192;            // 384
  float* s3    = s2 + 384;            // 768
  float* w1t   = s3 + 768;            // 4,800
  float* w2t   = w1t + 4800;          // 221,184
  float* w3t   = w2t + 221184;        // 884,736
  float* fcwt  = a1;                  // aliases a1 (dead after layer2)

  tr_w_kernel<<<dim3((4800 + 255) / 256), dim3(256), 0, stream>>>(w1, w1t, 64, 25);
  tr_w_kernel<<<dim3((221184 + 255) / 256), dim3(256), 0, stream>>>(w2, w2t, 128, 576);
  tr_w_kernel<<<dim3((884736 + 255) / 256), dim3(256), 0, stream>>>(w3, w3t, 256, 1152);
  sw2_kernel<<<dim3(6), dim3(256), 0, stream>>>(w1, w2, w3, s1, s2, s3);

  layer1_kernel<<<dim3(576, 16, 3), dim3(64), 0, stream>>>(x, w1t, s1, tri, a1);
  rbf3_kernel<64, 128, 48, 63, 1, 1>
      <<<dim3(144, 16, 3), dim3(128), 0, stream>>>(a1, w2t, s2, tri, a2);
  // a1 dead from here; reuse for transposed fc weights
  tr_fcw_kernel<<<dim3(144, 30), dim3(32, 8), 0, stream>>>(fcw, fcwt);
  rbf3_kernel<128, 256, 24, 152, 0, 2>
      <<<dim3(36, 16, 3), dim3(256), 0, stream>>>(a2, w3t, s3, tri, feats);
  fc_kernel<<<dim3(10, 16), dim3(256), 0, stream>>>(feats, fcwt, fcb, out);
}

// Round 4
// 643.417 us; speedup vs baseline: 4.8386x; 1.3011x over previous
//
#include <hip/hip_runtime.h>
#include <hip/hip_bf16.h>
#include <math.h>

typedef __attribute__((ext_vector_type(8))) short bf16x8;
typedef __attribute__((ext_vector_type(4))) float f32x4;

// ---------------- |w|^2 per filter row ----------------
__global__ __launch_bounds__(256) void sw2_kernel(
    const float* __restrict__ w1, const float* __restrict__ w2,
    const float* __restrict__ w3,
    float* __restrict__ s1, float* __restrict__ s2, float* __restrict__ s3) {
  int t = blockIdx.x * blockDim.x + threadIdx.x;
  if (t < 192) {
    const float* r = w1 + t * 25;
    float s = 0.f;
    for (int i = 0; i < 25; i++) s += r[i] * r[i];
    s1[t] = s;
  } else if (t < 192 + 384) {
    int u = t - 192;
    const float* r = w2 + u * 576;
    float s = 0.f;
    for (int i = 0; i < 576; i++) s += r[i] * r[i];
    s2[u] = s;
  } else if (t < 192 + 384 + 768) {
    int u = t - 576;
    const float* r = w3 + u * 1152;
    float s = 0.f;
    for (int i = 0; i < 1152; i++) s += r[i] * r[i];
    s3[u] = s;
  }
}

// ---------------- transpose conv weights (layer1 only) ---------------------
__global__ __launch_bounds__(256) void tr_w_kernel(
    const float* __restrict__ in, float* __restrict__ out, int O, int K) {
  int idx = blockIdx.x * blockDim.x + threadIdx.x;
  int total = 3 * O * K;
  if (idx >= total) return;
  int o = idx % O;
  int r = idx / O;
  int k = r % K;
  int br = r / K;
  out[((size_t)br * K + k) * O + o] = in[((size_t)br * O + o) * K + k];
}

// ---------------- transpose fc_w: [oo][br][c][pth] -> [oo][br][pth][c] -----
__global__ __launch_bounds__(256) void tr_fcw_kernel(
    const float* __restrict__ fcw, float* __restrict__ fcwt) {
  int tb = blockIdx.x;  // 18 pth-tiles x 8 c-tiles
  int pt = tb % 18, ct = tb / 18;
  int ob = blockIdx.y;  // oo*3+br
  __shared__ float tile[32][33];
  const float* src = fcw + (size_t)ob * 147456;
  float* dst = fcwt + (size_t)ob * 147456;
  int tx = threadIdx.x, ty = threadIdx.y;  // (32,8)
  int pth0 = pt * 32, c0 = ct * 32;
  for (int i = 0; i < 32; i += 8) {
    int c = c0 + ty + i;
    tile[ty + i][tx] = src[(size_t)c * 576 + pth0 + tx];
  }
  __syncthreads();
  for (int i = 0; i < 32; i += 8) {
    int pth = pth0 + ty + i;
    dst[(size_t)pth * 256 + c0 + tx] = tile[tx][ty + i];
  }
}

// ---------------- pack weights into MFMA-fragment layout, split hi/lo ------
// out[br][chunk][n][e], chunk = kpos*CC + cc, e in [0,32), c = cc*32+e
template <int CIN, int COUT>
__global__ __launch_bounds__(256) void pack_w_kernel(
    const float* __restrict__ w, unsigned short* __restrict__ bph,
    unsigned short* __restrict__ bpl) {
  constexpr int K = CIN * 9;
  constexpr int CC = CIN / 32;
  const int n = blockIdx.x, br = blockIdx.z;
  const int t = threadIdx.x;
  __shared__ float row[K];
  const float* src = w + ((size_t)br * COUT + n) * K;
  for (int i = t; i < K; i += 256) row[i] = src[i];
  __syncthreads();
  for (int i = t; i < K; i += 256) {
    int kpos = i / CIN;
    int e = i - kpos * CIN;  // = c
    float f = row[e * 9 + kpos];
    __hip_bfloat16 h = __float2bfloat16(f);
    float hf = __bfloat162float(h);
    __hip_bfloat16 l = __float2bfloat16(f - hf);
    size_t oidx =
        (((size_t)br * 9 * CC + (size_t)kpos * CC + (e >> 5)) * COUT + n) * 32 +
        (e & 31);
    bph[oidx] = *reinterpret_cast<unsigned short*>(&h);
    bpl[oidx] = *reinterpret_cast<unsigned short*>(&l);
  }
}

// ---------------- Layer 1 (unchanged from R2) ------------------------------
__global__ __launch_bounds__(64) void layer1_kernel(
    const float* __restrict__ x, const float* __restrict__ w1t,
    const float* __restrict__ sw2, const float* __restrict__ tri,
    float* __restrict__ a1) {
  const int gidx = blockIdx.x;  // 48 pool-rows x 12 col-quads
  const int gy = gidx / 12, gx = gidx % 12;
  const int n = blockIdx.y, br = blockIdx.z;
  const int o = threadIdx.x;
  const int lane = o & 63;

  __shared__ __align__(16) float win[6][12];
  __shared__ float sp2s[16];
  __shared__ unsigned int dbits[16][64];
  __shared__ float thrs[16];

  const int y0 = gy * 2 - 2, x0 = gx * 8 - 2;
  const float* xb = x + ((size_t)(n * 3 + br)) * 96 * 96;
  for (int idx = o; idx < 72; idx += 64) {
    int wy = idx / 12, wx = idx % 12;
    int y = y0 + wy, xx = x0 + wx;
    float v = 0.f;
    if (y >= 0 && y < 96 && xx >= 0 && xx < 96) v = xb[y * 96 + xx];
    win[wy][wx] = v;
  }
  __syncthreads();

  if (o < 16) {
    int py = o >> 3, px = o & 7;
    float s = 0.f;
#pragma unroll
    for (int ky = 0; ky < 5; ky++)
#pragma unroll
      for (int kx = 0; kx < 5; kx++) {
        float v = win[py + ky][px + kx];
        s += v * v;
      }
    sp2s[o] = s;
  }

  const float* wb = w1t + br * 25 * 64 + o;
  float wv[25];
#pragma unroll
  for (int j = 0; j < 25; j++) wv[j] = wb[j * 64];

  float acc[2][8] = {};
#pragma unroll
  for (int wy = 0; wy < 6; wy++) {
    float4 ra = *reinterpret_cast<const float4*>(&win[wy][0]);
    float4 rb = *reinterpret_cast<const float4*>(&win[wy][4]);
    float4 rc = *reinterpret_cast<const float4*>(&win[wy][8]);
    float r[12] = {ra.x, ra.y, ra.z, ra.w, rb.x, rb.y,
                   rb.z, rb.w, rc.x, rc.y, rc.z, rc.w};
#pragma unroll
    for (int py = 0; py < 2; py++) {
      int ky = wy - py;
      if (ky < 0 || ky > 4) continue;
#pragma unroll
      for (int kx = 0; kx < 5; kx++) {
        float wvv = wv[ky * 5 + kx];
#pragma unroll
        for (int px = 0; px < 8; px++) acc[py][px] += wvv * r[px + kx];
      }
    }
  }
  __syncthreads();

  float sw = sw2[br * 64 + o];
  float d[16];
#pragma unroll
  for (int p = 0; p < 16; p++) {
    float d2 = sp2s[p] + sw - 2.f * acc[p >> 3][p & 7];
    d[p] = sqrtf(fmaxf(d2, 1e-12f));
    dbits[p][o] = __float_as_uint(d[p]);
  }
  __syncthreads();

  for (int p = 0; p < 16; p++) {
    unsigned int v0 = dbits[p][lane];
    unsigned int prefix = 0;
    int rem = 31;
    for (int b = 30; b >= 0; --b) {
      unsigned int top = (prefix >> b) | 1u;
      int cnt = __popcll(__ballot((v0 >> b) == top));
      if (cnt > rem) prefix |= (1u << b);
      else rem -= cnt;
    }
    if (lane == 0) thrs[p] = __uint_as_float(prefix);
  }
  __syncthreads();

  const float w = tri[br * 3 + 0];
  const float A2[2][2] = {{0.9f, 0.93f}, {0.96f, 0.99f}};
#pragma unroll
  for (int g = 0; g < 4; g++) {
    float pooled = 0.f;
#pragma unroll
    for (int py = 0; py < 2; py++)
#pragma unroll
      for (int q = 0; q < 2; q++) {
        int p = py * 8 + g * 2 + q;
        float th = fminf(thrs[p], w);
        float dd = (d[p] > th) ? w : d[p];
        pooled += (1.f - dd / w) * A2[py][q];
      }
    pooled *= 0.25f;
    a1[((((size_t)(br * 16 + n)) * 48 + gy) * 48 + (gx * 4 + g)) * 64 + o] =
        pooled;
  }
}

// ---------------- Layers 2/3: MFMA split-bf16 RBF conv ---------------------
// block 256 = 4 waves; 8x8 conv-pixel tile; wave = 2 M-tiles x (NT/2) N-tiles
template <int CIN, int COUT, int HIN, int KRANK, int POOL, int LIDX>
__global__ __launch_bounds__(256) void mfma_rbf3(
    const float* __restrict__ in,                 // [3][16][HIN][HIN][CIN]
    const unsigned short* __restrict__ bph,       // packed hi
    const unsigned short* __restrict__ bpl,       // packed lo
    const float* __restrict__ sw2,                // [3][COUT]
    const float* __restrict__ tri,
    float* __restrict__ out) {
  constexpr int CC = CIN / 32;
  constexpr int NT = COUT / 16;
  constexpr int NTW = NT / 2;
  constexpr int PADC = COUT + 4;
  constexpr int WIN_USH = 100 * CIN;
  constexpr int WIN_BYTES = 2 * WIN_USH * 2;
  constexpr int DMAT_BYTES = 64 * PADC * 4;
  constexpr int UNI_BYTES = WIN_BYTES > DMAT_BYTES ? WIN_BYTES : DMAT_BYTES;

  __shared__ __align__(16) char uni[UNI_BYTES];
  __shared__ float cellsum[100];
  __shared__ float sp2[64];
  __shared__ float thrs[64];
  __shared__ float sw2s[COUT];

  unsigned short* winh = (unsigned short*)uni;
  unsigned short* winl = winh + WIN_USH;
  float* dmat = (float*)uni;  // aliases win after conv

  const int GX = HIN / 8;
  const int gy = blockIdx.x / GX, gx = blockIdx.x % GX;
  const int n = blockIdx.y, br = blockIdx.z;
  const int t = threadIdx.x;
  const int lane = t & 63;
  const int wvid = t >> 6;
  const int mg = wvid >> 1, ng = wvid & 1;

  const float w_ = tri[br * 3 + LIDX];
  const int y0 = gy * 8 - 1, x0 = gx * 8 - 1;
  const float* ib = in + ((size_t)(br * 16 + n)) * HIN * HIN * CIN;

  // ---- stage window (fp32 -> bf16 hi/lo, swizzled) + cellsums + sw2s ----
  for (int i = t; i < COUT; i += 256) sw2s[i] = sw2[br * COUT + i];
  if (t < 100) {
    const int wy = t / 10, wx = t - wy * 10;
    const int y = y0 + wy, x = x0 + wx;
    const bool ok = (y >= 0 && y < HIN && x >= 0 && x < HIN);
    const float* rp = ib + ((size_t)y * HIN + x) * CIN;
    const int sx = (wx & 7) << 3;
    float ss = 0.f;
    for (int cq = 0; cq < CIN / 4; cq++) {
      float4 v = ok ? *reinterpret_cast<const float4*>(rp + cq * 4)
                    : make_float4(0.f, 0.f, 0.f, 0.f);
      unsigned short hh[4], ll[4];
      float fv[4] = {v.x, v.y, v.z, v.w};
#pragma unroll
      for (int j = 0; j < 4; j++) {
        float f = fv[j];
        ss += f * f;
        __hip_bfloat16 h = __float2bfloat16(f);
        float hf = __bfloat162float(h);
        __hip_bfloat16 l = __float2bfloat16(f - hf);
        hh[j] = *reinterpret_cast<unsigned short*>(&h);
        ll[j] = *reinterpret_cast<unsigned short*>(&l);
      }
      int cst = (cq * 4) ^ sx;
      *reinterpret_cast<ushort4*>(&winh[t * CIN + cst]) =
          make_ushort4(hh[0], hh[1], hh[2], hh[3]);
      *reinterpret_cast<ushort4*>(&winl[t * CIN + cst]) =
          make_ushort4(ll[0], ll[1], ll[2], ll[3]);
    }
    cellsum[t] = ss;
  }
  __syncthreads();
  if (t < 64) {
    int py = t >> 3, px = t & 7;
    float s = 0.f;
#pragma unroll
    for (int ky = 0; ky < 3; ky++)
#pragma unroll
      for (int kx = 0; kx < 3; kx++) s += cellsum[(py + ky) * 10 + px + kx];
    sp2[t] = s;
  }

  // ---- conv: D[pixel][filter] += A(patch) . B(weight) --------------------
  const int pix0 = lane & 15;
  const int g8 = (lane >> 4) << 3;
  const int ppy = pix0 >> 3, ppx = pix0 & 7;

  f32x4 acc[2][NTW];
  f32x4 zz = {0.f, 0.f, 0.f, 0.f};
#pragma unroll
  for (int mt = 0; mt < 2; mt++)
#pragma unroll
    for (int nt = 0; nt < NTW; nt++) acc[mt][nt] = zz;

  const size_t bbase = (size_t)br * 9 * CC;
  const int nb0 = ng * (NTW * 16) + pix0;

  for (int kpos = 0; kpos < 9; kpos++) {
    const int ky = kpos / 3, kx = kpos - ky * 3;
    const int wx = ppx + kx;
    const int sx = (wx & 7) << 3;
    const int r0 = (mg * 4 + ppy + ky) * 10 + wx;  // mt=0 row; mt=1 adds 20
#pragma unroll
    for (int cc = 0; cc < CC; cc++) {
      const int chunk = kpos * CC + cc;
      const int cbase = ((cc << 5) + g8) ^ sx;
      bf16x8 ah0 = *reinterpret_cast<const bf16x8*>(&winh[r0 * CIN + cbase]);
      bf16x8 al0 = *reinterpret_cast<const bf16x8*>(&winl[r0 * CIN + cbase]);
      bf16x8 ah1 =
          *reinterpret_cast<const bf16x8*>(&winh[(r0 + 20) * CIN + cbase]);
      bf16x8 al1 =
          *reinterpret_cast<const bf16x8*>(&winl[(r0 + 20) * CIN + cbase]);
      const unsigned short* bp0 = bph + ((bbase + chunk) * COUT + nb0) * 32 + g8;
      const unsigned short* bp1 = bpl + ((bbase + chunk) * COUT + nb0) * 32 + g8;
#pragma unroll
      for (int np = 0; np < NTW / 2; np++) {
        bf16x8 bh0 = *reinterpret_cast<const bf16x8*>(bp0 + (np * 2 + 0) * 512);
        bf16x8 bl0 = *reinterpret_cast<const bf16x8*>(bp1 + (np * 2 + 0) * 512);
        bf16x8 bh1 = *reinterpret_cast<const bf16x8*>(bp0 + (np * 2 + 1) * 512);
        bf16x8 bl1 = *reinterpret_cast<const bf16x8*>(bp1 + (np * 2 + 1) * 512);
        acc[0][2 * np] = __builtin_amdgcn_mfma_f32_16x16x32_bf16(
            ah0, bh0, acc[0][2 * np], 0, 0, 0);
        acc[1][2 * np] = __builtin_amdgcn_mfma_f32_16x16x32_bf16(
            ah1, bh0, acc[1][2 * np], 0, 0, 0);
        acc[0][2 * np + 1] = __builtin_amdgcn_mfma_f32_16x16x32_bf16(
            ah0, bh1, acc[0][2 * np + 1], 0, 0, 0);
        acc[1][2 * np + 1] = __builtin_amdgcn_mfma_f32_16x16x32_bf16(
            ah1, bh1, acc[1][2 * np + 1], 0, 0, 0);
        acc[0][2 * np] = __builtin_amdgcn_mfma_f32_16x16x32_bf16(
            ah0, bl0, acc[0][2 * np], 0, 0, 0);
        acc[1][2 * np] = __builtin_amdgcn_mfma_f32_16x16x32_bf16(
            ah1, bl0, acc[1][2 * np], 0, 0, 0);
        acc[0][2 * np + 1] = __builtin_amdgcn_mfma_f32_16x16x32_bf16(
            ah0, bl1, acc[0][2 * np + 1], 0, 0, 0);
        acc[1][2 * np + 1] = __builtin_amdgcn_mfma_f32_16x16x32_bf16(
            ah1, bl1, acc[1][2 * np + 1], 0, 0, 0);
        acc[0][2 * np] = __builtin_amdgcn_mfma_f32_16x16x32_bf16(
            al0, bh0, acc[0][2 * np], 0, 0, 0);
        acc[1][2 * np] = __builtin_amdgcn_mfma_f32_16x16x32_bf16(
            al1, bh0, acc[1][2 * np], 0, 0, 0);
        acc[0][2 * np + 1] = __builtin_amdgcn_mfma_f32_16x16x32_bf16(
            al0, bh1, acc[0][2 * np + 1], 0, 0, 0);
        acc[1][2 * np + 1] = __builtin_amdgcn_mfma_f32_16x16x32_bf16(
            al1, bh1, acc[1][2 * np + 1], 0, 0, 0);
      }
    }
  }

  __syncthreads();  // conv reads done (win dead), sp2 visible

  // ---- d = sqrt(|p|^2 + |w|^2 - 2 dot) into dmat -------------------------
  const int rgrp = (lane >> 4) << 2;
#pragma unroll
  for (int mt = 0; mt < 2; mt++) {
    const int prow = (mg * 2 + mt) * 16 + rgrp;
#pragma unroll
    for (int nt = 0; nt < NTW; nt++) {
      const int col = ng * (NTW * 16) + nt * 16 + pix0;
      const float sw = sw2s[col];
#pragma unroll
      for (int rg = 0; rg < 4; rg++) {
        const int pix = prow + rg;
        float d2 = sp2[pix] + sw - 2.f * acc[mt][nt][rg];
        float d = sqrtf(fmaxf(d2, 1e-12f));
        dmat[pix * PADC + col] = d;
      }
    }
  }
  __syncthreads();

  // ---- per-pixel top-k threshold via wave radix-select -------------------
  for (int i = 0; i < 16; i++) {
    const int p = wvid * 16 + i;
    const float* rowp = &dmat[p * PADC];
    unsigned int v0, v1, v2, v3;
    if constexpr (COUT == 256) {
      float4 f = *reinterpret_cast<const float4*>(rowp + lane * 4);
      v0 = __float_as_uint(f.x);
      v1 = __float_as_uint(f.y);
      v2 = __float_as_uint(f.z);
      v3 = __float_as_uint(f.w);
    } else {
      float2 f = *reinterpret_cast<const float2*>(rowp + lane * 2);
      v0 = __float_as_uint(f.x);
      v1 = __float_as_uint(f.y);
      v2 = 0;
      v3 = 0;
    }
    unsigned int prefix = 0;
    int rem = KRANK;
    for (int b = 30; b >= 0; --b) {
      unsigned int top = (prefix >> b) | 1u;
      int cnt = __popcll(__ballot((v0 >> b) == top)) +
                __popcll(__ballot((v1 >> b) == top));
      if constexpr (COUT == 256) {
        cnt += __popcll(__ballot((v2 >> b) == top)) +
               __popcll(__ballot((v3 >> b) == top));
      }
      if (cnt > rem) prefix |= (1u << b);
      else rem -= cnt;
    }
    if (lane == 0) thrs[p] = __uint_as_float(prefix);
  }
  __syncthreads();

  // ---- activation (+ pool) + store ---------------------------------------
  if (POOL) {
    float* ob = out + ((size_t)(br * 16 + n)) * (HIN / 2) * (HIN / 2) * COUT;
    for (int i = t; i < 16 * COUT; i += 256) {
      int q = i / COUT;
      int ch = i - q * COUT;
      int qy = q >> 2, qx = q & 3;
      int p00 = qy * 16 + qx * 2;
      float d00 = dmat[p00 * PADC + ch];
      float d01 = dmat[(p00 + 1) * PADC + ch];
      float d10 = dmat[(p00 + 8) * PADC + ch];
      float d11 = dmat[(p00 + 9) * PADC + ch];
      float t00 = fminf(thrs[p00], w_);
      float t01 = fminf(thrs[p00 + 1], w_);
      float t10 = fminf(thrs[p00 + 8], w_);
      float t11 = fminf(thrs[p00 + 9], w_);
      float a00 = 1.f - ((d00 > t00) ? w_ : d00) / w_;
      float a01 = 1.f - ((d01 > t01) ? w_ : d01) / w_;
      float a10 = 1.f - ((d10 > t10) ? w_ : d10) / w_;
      float a11 = 1.f - ((d11 > t11) ? w_ : d11) / w_;
      float po =
          0.25f * (a00 * 0.9f + a01 * 0.93f + a10 * 0.96f + a11 * 0.99f);
      ob[((size_t)((gy * 4 + qy) * (HIN / 2) + gx * 4 + qx)) * COUT + ch] = po;
    }
  } else {
    float* ob = out + ((size_t)(br * 16 + n)) * HIN * HIN * COUT;
    for (int i = 0; i < 16; i++) {
      int r = wvid * 16 + i;
      float4 dv = *reinterpret_cast<const float4*>(&dmat[r * PADC + lane * 4]);
      float th = fminf(thrs[r], w_);
      float4 av;
      av.x = 1.f - ((dv.x > th) ? w_ : dv.x) / w_;
      av.y = 1.f - ((dv.y > th) ? w_ : dv.y) / w_;
      av.z = 1.f - ((dv.z > th) ? w_ : dv.z) / w_;
      av.w = 1.f - ((dv.w > th) ? w_ : dv.w) / w_;
      int oy = gy * 8 + (r >> 3), ox = gx * 8 + (r & 7);
      *reinterpret_cast<float4*>(&ob[((size_t)(oy * HIN + ox)) * COUT +
                                     lane * 4]) = av;
    }
  }
}

// ---------------- FC (unchanged) -------------------------------------------
__global__ __launch_bounds__(256) void fc_kernel(
    const float* __restrict__ feats, const float* __restrict__ fcwt,
    const float* __restrict__ fcb, float* __restrict__ outp) {
  const int oo = blockIdx.x;
  const int n = blockIdx.y;
  const int t = threadIdx.x;
  float s = 0.f;
  for (int br = 0; br < 3; br++) {
    const float4* fb = reinterpret_cast<const float4*>(
        feats + ((size_t)(br * 16 + n)) * 147456);
    const float4* wb = reinterpret_cast<const float4*>(
        fcwt + ((size_t)(oo * 3 + br)) * 147456);
    for (int i = t; i < 36864; i += 256) {
      float4 f = fb[i], w = wb[i];
      s += f.x * w.x + f.y * w.y + f.z * w.z + f.w * w.w;
    }
  }
  __shared__ float red[256];
  red[t] = s;
  __syncthreads();
  for (int st = 128; st > 0; st >>= 1) {
    if (t < st) red[t] += red[t + st];
    __syncthreads();
  }
  if (t == 0) outp[n * 10 + oo] = red[0] + fcb[oo];
}

// ---------------------------------------------------------------------------
extern "C" void kernel_launch(void* const* d_in, const int* in_sizes, int n_in,
                              void* d_out, int out_size, void* d_ws,
                              size_t ws_size, hipStream_t stream) {
  const float* x   = (const float*)d_in[0];
  const float* w1  = (const float*)d_in[1];
  const float* w2  = (const float*)d_in[2];
  const float* w3  = (const float*)d_in[3];
  const float* tri = (const float*)d_in[4];
  const float* fcw = (const float*)d_in[5];
  const float* fcb = (const float*)d_in[6];
  float* out = (float*)d_out;

  float* ws = (float*)d_ws;
  float* a1    = ws;                  // 7,077,888
  float* a2    = a1 + 7077888;        // 3,538,944
  float* feats = a2 + 3538944;        // 7,077,888
  float* s1    = feats + 7077888;     // 192
  float* s2    = s1 + 192;            // 384
  float* s3    = s2 + 384;            // 768
  float* w1t   = s3 + 768;            // 4,800
  unsigned short* bph2 = (unsigned short*)(w1t + 4800);  // 221,184 ushorts
  unsigned short* bpl2 = bph2 + 221184;
  unsigned short* bph3 = bpl2 + 221184;                  // 884,736
  unsigned short* bpl3 = bph3 + 884736;
  float* fcwt = a1;  // aliases a1 (dead after layer2)

  tr_w_kernel<<<dim3(19), dim3(256), 0, stream>>>(w1, w1t, 64, 25);
  sw2_kernel<<<dim3(6), dim3(256), 0, stream>>>(w1, w2, w3, s1, s2, s3);
  pack_w_kernel<64, 128><<<dim3(128, 1, 3), dim3(256), 0, stream>>>(w2, bph2,
                                                                    bpl2);
  pack_w_kernel<128, 256><<<dim3(256, 1, 3), dim3(256), 0, stream>>>(w3, bph3,
                                                                     bpl3);

  layer1_kernel<<<dim3(576, 16, 3), dim3(64), 0, stream>>>(x, w1t, s1, tri, a1);
  mfma_rbf3<64, 128, 48, 63, 1, 1>
      <<<dim3(36, 16, 3), dim3(256), 0, stream>>>(a1, bph2, bpl2, s2, tri, a2);
  // a1 dead; reuse for transposed fc weights
  tr_fcw_kernel<<<dim3(144, 30), dim3(32, 8), 0, stream>>>(fcw, fcwt);
  mfma_rbf3<128, 256, 24, 152, 0, 2>
      <<<dim3(9, 16, 3), dim3(256), 0, stream>>>(a2, bph3, bpl3, s3, tri, feats);
  fc_kernel<<<dim3(10, 16), dim3(256), 0, stream>>>(feats, fcwt, fcb, out);
}

// Round 5
// 549.377 us; speedup vs baseline: 5.6669x; 1.1712x over previous
//
#include <hip/hip_runtime.h>
#include <hip/hip_bf16.h>
#include <math.h>

typedef __attribute__((ext_vector_type(8))) short bf16x8;
typedef __attribute__((ext_vector_type(4))) float f32x4;

// ---------------- |w|^2 per filter row ----------------
__global__ __launch_bounds__(256) void sw2_kernel(
    const float* __restrict__ w1, const float* __restrict__ w2,
    const float* __restrict__ w3,
    float* __restrict__ s1, float* __restrict__ s2, float* __restrict__ s3) {
  int t = blockIdx.x * blockDim.x + threadIdx.x;
  if (t < 192) {
    const float* r = w1 + t * 25;
    float s = 0.f;
    for (int i = 0; i < 25; i++) s += r[i] * r[i];
    s1[t] = s;
  } else if (t < 192 + 384) {
    int u = t - 192;
    const float* r = w2 + u * 576;
    float s = 0.f;
    for (int i = 0; i < 576; i++) s += r[i] * r[i];
    s2[u] = s;
  } else if (t < 192 + 384 + 768) {
    int u = t - 576;
    const float* r = w3 + u * 1152;
    float s = 0.f;
    for (int i = 0; i < 1152; i++) s += r[i] * r[i];
    s3[u] = s;
  }
}

// ---------------- transpose conv weights (layer1 only) ---------------------
__global__ __launch_bounds__(256) void tr_w_kernel(
    const float* __restrict__ in, float* __restrict__ out, int O, int K) {
  int idx = blockIdx.x * blockDim.x + threadIdx.x;
  int total = 3 * O * K;
  if (idx >= total) return;
  int o = idx % O;
  int r = idx / O;
  int k = r % K;
  int br = r / K;
  out[((size_t)br * K + k) * O + o] = in[((size_t)br * O + o) * K + k];
}

// ---------------- transpose fc_w: [oo][br][c][pth] -> [oo][br][pth][c] -----
__global__ __launch_bounds__(256) void tr_fcw_kernel(
    const float* __restrict__ fcw, float* __restrict__ fcwt) {
  int tb = blockIdx.x;  // 18 pth-tiles x 8 c-tiles
  int pt = tb % 18, ct = tb / 18;
  int ob = blockIdx.y;  // oo*3+br
  __shared__ float tile[32][33];
  const float* src = fcw + (size_t)ob * 147456;
  float* dst = fcwt + (size_t)ob * 147456;
  int tx = threadIdx.x, ty = threadIdx.y;  // (32,8)
  int pth0 = pt * 32, c0 = ct * 32;
  for (int i = 0; i < 32; i += 8) {
    int c = c0 + ty + i;
    tile[ty + i][tx] = src[(size_t)c * 576 + pth0 + tx];
  }
  __syncthreads();
  for (int i = 0; i < 32; i += 8) {
    int pth = pth0 + ty + i;
    dst[(size_t)pth * 256 + c0 + tx] = tile[tx][ty + i];
  }
}

// ---------------- pack weights into MFMA-fragment layout, split hi/lo ------
template <int CIN, int COUT>
__global__ __launch_bounds__(256) void pack_w_kernel(
    const float* __restrict__ w, unsigned short* __restrict__ bph,
    unsigned short* __restrict__ bpl) {
  constexpr int K = CIN * 9;
  constexpr int CC = CIN / 32;
  const int n = blockIdx.x, br = blockIdx.z;
  const int t = threadIdx.x;
  __shared__ float row[K];
  const float* src = w + ((size_t)br * COUT + n) * K;
  for (int i = t; i < K; i += 256) row[i] = src[i];
  __syncthreads();
  for (int i = t; i < K; i += 256) {
    int kpos = i / CIN;
    int e = i - kpos * CIN;  // = c
    float f = row[e * 9 + kpos];
    __hip_bfloat16 h = __float2bfloat16(f);
    float hf = __bfloat162float(h);
    __hip_bfloat16 l = __float2bfloat16(f - hf);
    size_t oidx =
        (((size_t)br * 9 * CC + (size_t)kpos * CC + (e >> 5)) * COUT + n) * 32 +
        (e & 31);
    bph[oidx] = *reinterpret_cast<unsigned short*>(&h);
    bpl[oidx] = *reinterpret_cast<unsigned short*>(&l);
  }
}

// ---- bitonic sort across 64 lanes (ascending), return element 32 ----------
__device__ __forceinline__ float wave_kth32(float v, int lane) {
#pragma unroll
  for (int k = 2; k <= 64; k <<= 1) {
#pragma unroll
    for (int j = k >> 1; j > 0; j >>= 1) {
      float o = __shfl_xor(v, j, 64);
      bool keep_min = (((lane & j) == 0) == ((lane & k) == 0));
      float mn = fminf(v, o), mx = fmaxf(v, o);
      v = keep_min ? mn : mx;
    }
  }
  return __shfl(v, 32, 64);
}

// ---------------- Layer 1: 1ch 5x5 pad2 -> 64ch, crelu(rank31), pool -------
// 256 threads = 4 waves; block covers 8x8 conv pixels (4x4 pool outputs);
// wave w handles conv rows 2w..2w+1.
__global__ __launch_bounds__(256) void layer1_kernel(
    const float* __restrict__ x,    // [16][3][96][96]
    const float* __restrict__ w1t,  // [3][25][64]
    const float* __restrict__ sw2v, // [3][64]
    const float* __restrict__ tri,  // [3][3]
    float* __restrict__ a1)         // [3][16][48][48][64]
{
  const int gidx = blockIdx.x;  // 12 x 12 tiles
  const int gy = gidx / 12, gx = gidx % 12;
  const int n = blockIdx.y, br = blockIdx.z;
  const int t = threadIdx.x;
  const int lane = t & 63, wid = t >> 6;

  __shared__ __align__(16) float win[12][12];
  __shared__ float sp2s[64];

  const int y0 = gy * 8 - 2, x0 = gx * 8 - 2;
  const float* xb = x + ((size_t)(n * 3 + br)) * 96 * 96;
  if (t < 144) {
    int wy = t / 12, wx = t - (t / 12) * 12;
    int y = y0 + wy, xx = x0 + wx;
    float v = 0.f;
    if (y >= 0 && y < 96 && xx >= 0 && xx < 96) v = xb[y * 96 + xx];
    win[wy][wx] = v;
  }
  __syncthreads();

  if (t < 64) {
    int py = t >> 3, px = t & 7;
    float s = 0.f;
#pragma unroll
    for (int ky = 0; ky < 5; ky++)
#pragma unroll
      for (int kx = 0; kx < 5; kx++) {
        float v = win[py + ky][px + kx];
        s += v * v;
      }
    sp2s[t] = s;
  }
  __syncthreads();

  const float* wb = w1t + br * 25 * 64 + lane;
  float wv[25];
#pragma unroll
  for (int j = 0; j < 25; j++) wv[j] = wb[j * 64];

  float acc[2][8] = {};
#pragma unroll
  for (int wyy = 0; wyy < 6; wyy++) {
    const int wy = wid * 2 + wyy;
    float4 ra = *reinterpret_cast<const float4*>(&win[wy][0]);
    float4 rb = *reinterpret_cast<const float4*>(&win[wy][4]);
    float4 rc = *reinterpret_cast<const float4*>(&win[wy][8]);
    float r[12] = {ra.x, ra.y, ra.z, ra.w, rb.x, rb.y,
                   rb.z, rb.w, rc.x, rc.y, rc.z, rc.w};
#pragma unroll
    for (int py = 0; py < 2; py++) {
      int ky = wyy - py;
      if (ky < 0 || ky > 4) continue;
#pragma unroll
      for (int kx = 0; kx < 5; kx++) {
        float wvv = wv[ky * 5 + kx];
#pragma unroll
        for (int px = 0; px < 8; px++) acc[py][px] += wvv * r[px + kx];
      }
    }
  }

  const float sw = sw2v[br * 64 + lane];
  const float w_ = tri[br * 3 + 0];
  const float A2[2][2] = {{0.9f, 0.93f}, {0.96f, 0.99f}};
  float pooled[4] = {0.f, 0.f, 0.f, 0.f};
#pragma unroll
  for (int p = 0; p < 16; p++) {
    const int py = p >> 3, px = p & 7;
    float d2 = sp2s[(wid * 2 + py) * 8 + px] + sw - 2.f * acc[py][px];
    float dd = sqrtf(fmaxf(d2, 1e-12f));
    float thr = wave_kth32(dd, lane);
    float th = fminf(thr, w_);
    float a = 1.f - ((dd > th) ? w_ : dd) / w_;
    pooled[px >> 1] += a * A2[py][px & 1];
  }
#pragma unroll
  for (int g = 0; g < 4; g++) {
    a1[((((size_t)(br * 16 + n)) * 48 + (gy * 4 + wid)) * 48 + (gx * 4 + g)) *
           64 + lane] = pooled[g] * 0.25f;
  }
}

// ---------------- Layers 2/3: MFMA split-bf16 RBF conv ---------------------
// 256 threads = 4 waves; block covers 4 rows x 8 cols of conv pixels.
// wave = (mg: which 16-pixel M-tile) x (ng: which COUT/2 N-half).
template <int CIN, int COUT, int HIN, int KRANK, int POOL, int LIDX>
__global__ __launch_bounds__(256) void mfma_rbf3(
    const float* __restrict__ in,            // [3][16][HIN][HIN][CIN]
    const unsigned short* __restrict__ bph,  // packed hi
    const unsigned short* __restrict__ bpl,  // packed lo
    const float* __restrict__ sw2v,          // [3][COUT]
    const float* __restrict__ tri,
    float* __restrict__ out) {
  constexpr int CC = CIN / 32;
  constexpr int NT = COUT / 16;
  constexpr int NTW = NT / 2;
  constexpr int PADC = COUT + 4;
  constexpr int WIN_USH = 60 * CIN;               // per buffer (h or l)
  constexpr int WIN_BYTES = 2 * WIN_USH * 2;      // h + l
  constexpr int DMAT_BYTES = 32 * PADC * 4;
  constexpr int UNI_BYTES = WIN_BYTES > DMAT_BYTES ? WIN_BYTES : DMAT_BYTES;

  __shared__ __align__(16) char uni[UNI_BYTES];
  __shared__ float cellq[60][4];
  __shared__ float cellsum[60];
  __shared__ float sp2[32];
  __shared__ float thrs[32];
  __shared__ float sw2s[COUT];

  unsigned short* winh = (unsigned short*)uni;
  unsigned short* winl = winh + WIN_USH;
  float* dmat = (float*)uni;  // aliases win after conv

  const int GX = HIN / 8;
  const int gy = blockIdx.x / GX, gx = blockIdx.x % GX;
  const int n = blockIdx.y, br = blockIdx.z;
  const int t = threadIdx.x;
  const int lane = t & 63;
  const int wvid = t >> 6;
  const int mg = wvid >> 1, ng = wvid & 1;

  const float w_ = tri[br * 3 + LIDX];
  const int y0 = gy * 4 - 1, x0 = gx * 8 - 1;
  const float* ib = in + ((size_t)(br * 16 + n)) * HIN * HIN * CIN;

  // ---- stage window (fp32 -> bf16 hi/lo, swizzled) + cell partial sums ----
  for (int i = t; i < COUT; i += 256) sw2s[i] = sw2v[br * COUT + i];
  if (t < 240) {
    const int cell = t >> 2, q = t & 3;
    const int wy = cell / 10, wx = cell - (cell / 10) * 10;
    const int y = y0 + wy, xx = x0 + wx;
    const bool ok = (y >= 0 && y < HIN && xx >= 0 && xx < HIN);
    const float* rp = ib + ((size_t)y * HIN + xx) * CIN + q * (CIN / 4);
    const int sx = (wx & 7) << 3;
    float ss = 0.f;
#pragma unroll
    for (int cq = 0; cq < CIN / 16; cq++) {
      float4 v = ok ? *reinterpret_cast<const float4*>(rp + cq * 4)
                    : make_float4(0.f, 0.f, 0.f, 0.f);
      unsigned short hh[4], ll[4];
      float fv[4] = {v.x, v.y, v.z, v.w};
#pragma unroll
      for (int j = 0; j < 4; j++) {
        float f = fv[j];
        ss += f * f;
        __hip_bfloat16 h = __float2bfloat16(f);
        float hf = __bfloat162float(h);
        __hip_bfloat16 l = __float2bfloat16(f - hf);
        hh[j] = *reinterpret_cast<unsigned short*>(&h);
        ll[j] = *reinterpret_cast<unsigned short*>(&l);
      }
      int c = q * (CIN / 4) + cq * 4;
      int cst = c ^ sx;
      *reinterpret_cast<ushort4*>(&winh[cell * CIN + cst]) =
          make_ushort4(hh[0], hh[1], hh[2], hh[3]);
      *reinterpret_cast<ushort4*>(&winl[cell * CIN + cst]) =
          make_ushort4(ll[0], ll[1], ll[2], ll[3]);
    }
    cellq[cell][q] = ss;
  }
  __syncthreads();
  if (t < 60)
    cellsum[t] = cellq[t][0] + cellq[t][1] + cellq[t][2] + cellq[t][3];
  __syncthreads();
  if (t < 32) {
    int py = t >> 3, px = t & 7;
    float s = 0.f;
#pragma unroll
    for (int ky = 0; ky < 3; ky++)
#pragma unroll
      for (int kx = 0; kx < 3; kx++) s += cellsum[(py + ky) * 10 + px + kx];
    sp2[t] = s;
  }

  // ---- conv: D[pixel][filter] += A(patch) . B(weight), 3-term split ------
  const int pix0 = lane & 15;
  const int g8 = (lane >> 4) << 3;
  const int ppy = pix0 >> 3, ppx = pix0 & 7;

  f32x4 acc[NTW];
  f32x4 zz = {0.f, 0.f, 0.f, 0.f};
#pragma unroll
  for (int nt = 0; nt < NTW; nt++) acc[nt] = zz;

  const size_t bbase = (size_t)br * 9 * CC;
  const int nb0 = ng * (NTW * 16) + pix0;

  for (int kpos = 0; kpos < 9; kpos++) {
    const int ky = kpos / 3, kx = kpos - ky * 3;
    const int wx = ppx + kx;
    const int sx = (wx & 7) << 3;
    const int r0 = (mg * 2 + ppy + ky) * 10 + wx;
#pragma unroll
    for (int cc = 0; cc < CC; cc++) {
      const int chunk = kpos * CC + cc;
      const int cbase = ((cc << 5) + g8) ^ sx;
      bf16x8 ah = *reinterpret_cast<const bf16x8*>(&winh[r0 * CIN + cbase]);
      bf16x8 al = *reinterpret_cast<const bf16x8*>(&winl[r0 * CIN + cbase]);
      const unsigned short* bp0 =
          bph + ((bbase + chunk) * COUT + nb0) * 32 + g8;
      const unsigned short* bp1 =
          bpl + ((bbase + chunk) * COUT + nb0) * 32 + g8;
#pragma unroll
      for (int np = 0; np < NTW / 2; np++) {
        bf16x8 bh0 = *reinterpret_cast<const bf16x8*>(bp0 + (np * 2 + 0) * 512);
        bf16x8 bl0 = *reinterpret_cast<const bf16x8*>(bp1 + (np * 2 + 0) * 512);
        bf16x8 bh1 = *reinterpret_cast<const bf16x8*>(bp0 + (np * 2 + 1) * 512);
        bf16x8 bl1 = *reinterpret_cast<const bf16x8*>(bp1 + (np * 2 + 1) * 512);
        acc[2 * np] = __builtin_amdgcn_mfma_f32_16x16x32_bf16(
            ah, bh0, acc[2 * np], 0, 0, 0);
        acc[2 * np + 1] = __builtin_amdgcn_mfma_f32_16x16x32_bf16(
            ah, bh1, acc[2 * np + 1], 0, 0, 0);
        acc[2 * np] = __builtin_amdgcn_mfma_f32_16x16x32_bf16(
            ah, bl0, acc[2 * np], 0, 0, 0);
        acc[2 * np + 1] = __builtin_amdgcn_mfma_f32_16x16x32_bf16(
            ah, bl1, acc[2 * np + 1], 0, 0, 0);
        acc[2 * np] = __builtin_amdgcn_mfma_f32_16x16x32_bf16(
            al, bh0, acc[2 * np], 0, 0, 0);
        acc[2 * np + 1] = __builtin_amdgcn_mfma_f32_16x16x32_bf16(
            al, bh1, acc[2 * np + 1], 0, 0, 0);
      }
    }
  }

  __syncthreads();  // conv reads of win done (alias!), sp2 visible

  // ---- d = sqrt(|p|^2 + |w|^2 - 2 dot) into dmat -------------------------
  const int rgrp = (lane >> 4) << 2;
  const int prow = mg * 16 + rgrp;
#pragma unroll
  for (int nt = 0; nt < NTW; nt++) {
    const int col = ng * (NTW * 16) + nt * 16 + pix0;
    const float sw = sw2s[col];
#pragma unroll
    for (int rg = 0; rg < 4; rg++) {
      const int pix = prow + rg;
      float d2 = sp2[pix] + sw - 2.f * acc[nt][rg];
      dmat[pix * PADC + col] = sqrtf(fmaxf(d2, 1e-12f));
    }
  }
  __syncthreads();

  // ---- per-pixel top-k threshold: radix select, 2 pixels fused for ILP ---
  for (int i = 0; i < 8; i += 2) {
    const int p0 = wvid * 8 + i, p1 = p0 + 1;
    unsigned int a0, a1v, a2, a3, b0, b1, b2, b3;
    if constexpr (COUT == 256) {
      float4 fa = *reinterpret_cast<const float4*>(&dmat[p0 * PADC + lane * 4]);
      float4 fb = *reinterpret_cast<const float4*>(&dmat[p1 * PADC + lane * 4]);
      a0 = __float_as_uint(fa.x); a1v = __float_as_uint(fa.y);
      a2 = __float_as_uint(fa.z); a3 = __float_as_uint(fa.w);
      b0 = __float_as_uint(fb.x); b1 = __float_as_uint(fb.y);
      b2 = __float_as_uint(fb.z); b3 = __float_as_uint(fb.w);
    } else {
      float2 fa = *reinterpret_cast<const float2*>(&dmat[p0 * PADC + lane * 2]);
      float2 fb = *reinterpret_cast<const float2*>(&dmat[p1 * PADC + lane * 2]);
      a0 = __float_as_uint(fa.x); a1v = __float_as_uint(fa.y);
      b0 = __float_as_uint(fb.x); b1 = __float_as_uint(fb.y);
      a2 = a3 = b2 = b3 = 0;
    }
    unsigned int pre0 = 0, pre1 = 0;
    int rem0 = KRANK, rem1 = KRANK;
    for (int b = 30; b >= 0; --b) {
      unsigned int top0 = (pre0 >> b) | 1u;
      unsigned int top1 = (pre1 >> b) | 1u;
      int c0 = __popcll(__ballot((a0 >> b) == top0)) +
               __popcll(__ballot((a1v >> b) == top0));
      int c1 = __popcll(__ballot((b0 >> b) == top1)) +
               __popcll(__ballot((b1 >> b) == top1));
      if constexpr (COUT == 256) {
        c0 += __popcll(__ballot((a2 >> b) == top0)) +
              __popcll(__ballot((a3 >> b) == top0));
        c1 += __popcll(__ballot((b2 >> b) == top1)) +
              __popcll(__ballot((b3 >> b) == top1));
      }
      if (c0 > rem0) pre0 |= (1u << b); else rem0 -= c0;
      if (c1 > rem1) pre1 |= (1u << b); else rem1 -= c1;
    }
    if (lane == 0) {
      thrs[p0] = __uint_as_float(pre0);
      thrs[p1] = __uint_as_float(pre1);
    }
  }
  __syncthreads();

  // ---- activation (+ pool) + store ---------------------------------------
  if (POOL) {
    const int GW = HIN / 2;
    float* ob = out + ((size_t)(br * 16 + n)) * GW * GW * COUT;
    for (int i = t; i < 8 * COUT; i += 256) {
      int q = i / COUT;
      int ch = i - q * COUT;
      int qy = q >> 2, qx = q & 3;
      int p00 = qy * 16 + qx * 2;
      float d00 = dmat[p00 * PADC + ch];
      float d01 = dmat[(p00 + 1) * PADC + ch];
      float d10 = dmat[(p00 + 8) * PADC + ch];
      float d11 = dmat[(p00 + 9) * PADC + ch];
      float t00 = fminf(thrs[p00], w_);
      float t01 = fminf(thrs[p00 + 1], w_);
      float t10 = fminf(thrs[p00 + 8], w_);
      float t11 = fminf(thrs[p00 + 9], w_);
      float a00 = 1.f - ((d00 > t00) ? w_ : d00) / w_;
      float a01 = 1.f - ((d01 > t01) ? w_ : d01) / w_;
      float a10 = 1.f - ((d10 > t10) ? w_ : d10) / w_;
      float a11 = 1.f - ((d11 > t11) ? w_ : d11) / w_;
      float po =
          0.25f * (a00 * 0.9f + a01 * 0.93f + a10 * 0.96f + a11 * 0.99f);
      ob[((size_t)((gy * 2 + qy) * GW + gx * 4 + qx)) * COUT + ch] = po;
    }
  } else {
    float* ob = out + ((size_t)(br * 16 + n)) * HIN * HIN * COUT;
    for (int i = 0; i < 8; i++) {
      int r = wvid * 8 + i;
      float4 dv = *reinterpret_cast<const float4*>(&dmat[r * PADC + lane * 4]);
      float th = fminf(thrs[r], w_);
      float4 av;
      av.x = 1.f - ((dv.x > th) ? w_ : dv.x) / w_;
      av.y = 1.f - ((dv.y > th) ? w_ : dv.y) / w_;
      av.z = 1.f - ((dv.z > th) ? w_ : dv.z) / w_;
      av.w = 1.f - ((dv.w > th) ? w_ : dv.w) / w_;
      int oy = gy * 4 + (r >> 3), ox = gx * 8 + (r & 7);
      *reinterpret_cast<float4*>(
          &ob[((size_t)(oy * HIN + ox)) * COUT + lane * 4]) = av;
    }
  }
}

// ---------------- FC: split-K partials + reduce ----------------------------
__global__ __launch_bounds__(256) void fc_partial_kernel(
    const float* __restrict__ feats, const float* __restrict__ fcwt,
    float* __restrict__ partial) {
  const int oo = blockIdx.x;  // 0..9
  const int n = blockIdx.y;   // 0..15
  const int s = blockIdx.z;   // 0..7
  const int t = threadIdx.x;
  const int i0 = s * 4608;
  float acc = 0.f;
  for (int br = 0; br < 3; br++) {
    const float4* fb = reinterpret_cast<const float4*>(
        feats + ((size_t)(br * 16 + n)) * 147456);
    const float4* wb = reinterpret_cast<const float4*>(
        fcwt + ((size_t)(oo * 3 + br)) * 147456);
    for (int i = i0 + t; i < i0 + 4608; i += 256) {
      float4 f = fb[i], w = wb[i];
      acc += f.x * w.x + f.y * w.y + f.z * w.z + f.w * w.w;
    }
  }
  __shared__ float red[256];
  red[t] = acc;
  __syncthreads();
  for (int st = 128; st > 0; st >>= 1) {
    if (t < st) red[t] += red[t + st];
    __syncthreads();
  }
  if (t == 0) partial[((size_t)oo * 16 + n) * 8 + s] = red[0];
}

__global__ __launch_bounds__(256) void fc_final_kernel(
    const float* __restrict__ partial, const float* __restrict__ fcb,
    float* __restrict__ outp) {
  const int t = threadIdx.x;
  if (t < 160) {
    int oo = t / 16, n = t % 16;
    float s = 0.f;
#pragma unroll
    for (int q = 0; q < 8; q++) s += partial[((size_t)oo * 16 + n) * 8 + q];
    outp[n * 10 + oo] = s + fcb[oo];
  }
}

// ---------------------------------------------------------------------------
extern "C" void kernel_launch(void* const* d_in, const int* in_sizes, int n_in,
                              void* d_out, int out_size, void* d_ws,
                              size_t ws_size, hipStream_t stream) {
  const float* x   = (const float*)d_in[0];
  const float* w1  = (const float*)d_in[1];
  const float* w2  = (const float*)d_in[2];
  const float* w3  = (const float*)d_in[3];
  const float* tri = (const float*)d_in[4];
  const float* fcw = (const float*)d_in[5];
  const float* fcb = (const float*)d_in[6];
  float* out = (float*)d_out;

  float* ws = (float*)d_ws;
  float* a1    = ws;                  // 7,077,888
  float* a2    = a1 + 7077888;        // 3,538,944
  float* feats = a2 + 3538944;        // 7,077,888
  float* s1    = feats + 7077888;     // 192
  float* s2    = s1 + 192;            // 384
  float* s3    = s2 + 384;            // 768
  float* w1t   = s3 + 768;            // 4,800
  unsigned short* bph2 = (unsigned short*)(w1t + 4800);  // 221,184 ushorts
  unsigned short* bpl2 = bph2 + 221184;
  unsigned short* bph3 = bpl2 + 221184;                  // 884,736
  unsigned short* bpl3 = bph3 + 884736;
  float* partial = (float*)(bpl3 + 884736);              // 1,280 floats
  float* fcwt = a1;  // aliases a1 (dead after layer2)

  tr_w_kernel<<<dim3(19), dim3(256), 0, stream>>>(w1, w1t, 64, 25);
  sw2_kernel<<<dim3(6), dim3(256), 0, stream>>>(w1, w2, w3, s1, s2, s3);
  pack_w_kernel<64, 128><<<dim3(128, 1, 3), dim3(256), 0, stream>>>(w2, bph2,
                                                                    bpl2);
  pack_w_kernel<128, 256><<<dim3(256, 1, 3), dim3(256), 0, stream>>>(w3, bph3,
                                                                     bpl3);

  layer1_kernel<<<dim3(144, 16, 3), dim3(256), 0, stream>>>(x, w1t, s1, tri,
                                                            a1);
  mfma_rbf3<64, 128, 48, 63, 1, 1>
      <<<dim3(72, 16, 3), dim3(256), 0, stream>>>(a1, bph2, bpl2, s2, tri, a2);
  // a1 dead; reuse for transposed fc weights
  tr_fcw_kernel<<<dim3(144, 30), dim3(32, 8), 0, stream>>>(fcw, fcwt);
  mfma_rbf3<128, 256, 24, 152, 0, 2>
      <<<dim3(18, 16, 3), dim3(256), 0, stream>>>(a2, bph3, bpl3, s3, tri,
                                                  feats);
  fc_partial_kernel<<<dim3(10, 16, 8), dim3(256), 0, stream>>>(feats, fcwt,
                                                               partial);
  fc_final_kernel<<<dim3(1), dim3(256), 0, stream>>>(partial, fcb, out);
}

// Round 6
// 450.475 us; speedup vs baseline: 6.9110x; 1.2195x over previous
//
#include <hip/hip_runtime.h>
#include <hip/hip_bf16.h>
#include <math.h>

typedef __attribute__((ext_vector_type(8))) short bf16x8;
typedef __attribute__((ext_vector_type(4))) float f32x4;

// ---------------- |w|^2 per filter row ----------------
__global__ __launch_bounds__(256) void sw2_kernel(
    const float* __restrict__ w1, const float* __restrict__ w2,
    const float* __restrict__ w3,
    float* __restrict__ s1, float* __restrict__ s2, float* __restrict__ s3) {
  int t = blockIdx.x * blockDim.x + threadIdx.x;
  if (t < 192) {
    const float* r = w1 + t * 25;
    float s = 0.f;
    for (int i = 0; i < 25; i++) s += r[i] * r[i];
    s1[t] = s;
  } else if (t < 192 + 384) {
    int u = t - 192;
    const float* r = w2 + u * 576;
    float s = 0.f;
    for (int i = 0; i < 576; i++) s += r[i] * r[i];
    s2[u] = s;
  } else if (t < 192 + 384 + 768) {
    int u = t - 576;
    const float* r = w3 + u * 1152;
    float s = 0.f;
    for (int i = 0; i < 1152; i++) s += r[i] * r[i];
    s3[u] = s;
  }
}

// ---------------- transpose conv weights (layer1 only) ---------------------
__global__ __launch_bounds__(256) void tr_w_kernel(
    const float* __restrict__ in, float* __restrict__ out, int O, int K) {
  int idx = blockIdx.x * blockDim.x + threadIdx.x;
  int total = 3 * O * K;
  if (idx >= total) return;
  int o = idx % O;
  int r = idx / O;
  int k = r % K;
  int br = r / K;
  out[((size_t)br * K + k) * O + o] = in[((size_t)br * O + o) * K + k];
}

// ---------------- transpose fc_w: [oo][br][c][pth] -> [oo][br][pth][c] -----
__global__ __launch_bounds__(256) void tr_fcw_kernel(
    const float* __restrict__ fcw, float* __restrict__ fcwt) {
  int tb = blockIdx.x;  // 18 pth-tiles x 8 c-tiles
  int pt = tb % 18, ct = tb / 18;
  int ob = blockIdx.y;  // oo*3+br
  __shared__ float tile[32][33];
  const float* src = fcw + (size_t)ob * 147456;
  float* dst = fcwt + (size_t)ob * 147456;
  int tx = threadIdx.x, ty = threadIdx.y;  // (32,8)
  int pth0 = pt * 32, c0 = ct * 32;
  for (int i = 0; i < 32; i += 8) {
    int c = c0 + ty + i;
    tile[ty + i][tx] = src[(size_t)c * 576 + pth0 + tx];
  }
  __syncthreads();
  for (int i = 0; i < 32; i += 8) {
    int pth = pth0 + ty + i;
    dst[(size_t)pth * 256 + c0 + tx] = tile[tx][ty + i];
  }
}

// ---------------- pack weights into MFMA-fragment layout, split hi/lo ------
template <int CIN, int COUT>
__global__ __launch_bounds__(256) void pack_w_kernel(
    const float* __restrict__ w, unsigned short* __restrict__ bph,
    unsigned short* __restrict__ bpl) {
  constexpr int K = CIN * 9;
  constexpr int CC = CIN / 32;
  const int n = blockIdx.x, br = blockIdx.z;
  const int t = threadIdx.x;
  __shared__ float row[K];
  const float* src = w + ((size_t)br * COUT + n) * K;
  for (int i = t; i < K; i += 256) row[i] = src[i];
  __syncthreads();
  for (int i = t; i < K; i += 256) {
    int kpos = i / CIN;
    int e = i - kpos * CIN;  // = c
    float f = row[e * 9 + kpos];
    __hip_bfloat16 h = __float2bfloat16(f);
    float hf = __bfloat162float(h);
    __hip_bfloat16 l = __float2bfloat16(f - hf);
    size_t oidx =
        (((size_t)br * 9 * CC + (size_t)kpos * CC + (e >> 5)) * COUT + n) * 32 +
        (e & 31);
    bph[oidx] = *reinterpret_cast<unsigned short*>(&h);
    bpl[oidx] = *reinterpret_cast<unsigned short*>(&l);
  }
}

// ---- bitonic sort across 64 lanes (ascending), return element 32 ----------
__device__ __forceinline__ float wave_kth32(float v, int lane) {
#pragma unroll
  for (int k = 2; k <= 64; k <<= 1) {
#pragma unroll
    for (int j = k >> 1; j > 0; j >>= 1) {
      float o = __shfl_xor(v, j, 64);
      bool keep_min = (((lane & j) == 0) == ((lane & k) == 0));
      float mn = fminf(v, o), mx = fmaxf(v, o);
      v = keep_min ? mn : mx;
    }
  }
  return __shfl(v, 32, 64);
}

// ---------------- Layer 1: 1ch 5x5 pad2 -> 64ch, crelu(rank31), pool -------
__global__ __launch_bounds__(256) void layer1_kernel(
    const float* __restrict__ x,    // [16][3][96][96]
    const float* __restrict__ w1t,  // [3][25][64]
    const float* __restrict__ sw2v, // [3][64]
    const float* __restrict__ tri,  // [3][3]
    float* __restrict__ a1)         // [3][16][48][48][64]
{
  const int gidx = blockIdx.x;  // 12 x 12 tiles
  const int gy = gidx / 12, gx = gidx % 12;
  const int n = blockIdx.y, br = blockIdx.z;
  const int t = threadIdx.x;
  const int lane = t & 63, wid = t >> 6;

  __shared__ __align__(16) float win[12][12];
  __shared__ float sp2s[64];

  const int y0 = gy * 8 - 2, x0 = gx * 8 - 2;
  const float* xb = x + ((size_t)(n * 3 + br)) * 96 * 96;
  if (t < 144) {
    int wy = t / 12, wx = t - (t / 12) * 12;
    int y = y0 + wy, xx = x0 + wx;
    float v = 0.f;
    if (y >= 0 && y < 96 && xx >= 0 && xx < 96) v = xb[y * 96 + xx];
    win[wy][wx] = v;
  }
  __syncthreads();

  if (t < 64) {
    int py = t >> 3, px = t & 7;
    float s = 0.f;
#pragma unroll
    for (int ky = 0; ky < 5; ky++)
#pragma unroll
      for (int kx = 0; kx < 5; kx++) {
        float v = win[py + ky][px + kx];
        s += v * v;
      }
    sp2s[t] = s;
  }
  __syncthreads();

  const float* wb = w1t + br * 25 * 64 + lane;
  float wv[25];
#pragma unroll
  for (int j = 0; j < 25; j++) wv[j] = wb[j * 64];

  float acc[2][8] = {};
#pragma unroll
  for (int wyy = 0; wyy < 6; wyy++) {
    const int wy = wid * 2 + wyy;
    float4 ra = *reinterpret_cast<const float4*>(&win[wy][0]);
    float4 rb = *reinterpret_cast<const float4*>(&win[wy][4]);
    float4 rc = *reinterpret_cast<const float4*>(&win[wy][8]);
    float r[12] = {ra.x, ra.y, ra.z, ra.w, rb.x, rb.y,
                   rb.z, rb.w, rc.x, rc.y, rc.z, rc.w};
#pragma unroll
    for (int py = 0; py < 2; py++) {
      int ky = wyy - py;
      if (ky < 0 || ky > 4) continue;
#pragma unroll
      for (int kx = 0; kx < 5; kx++) {
        float wvv = wv[ky * 5 + kx];
#pragma unroll
        for (int px = 0; px < 8; px++) acc[py][px] += wvv * r[px + kx];
      }
    }
  }

  const float sw = sw2v[br * 64 + lane];
  const float w_ = tri[br * 3 + 0];
  const float A2[2][2] = {{0.9f, 0.93f}, {0.96f, 0.99f}};
  float pooled[4] = {0.f, 0.f, 0.f, 0.f};
#pragma unroll
  for (int p = 0; p < 16; p++) {
    const int py = p >> 3, px = p & 7;
    float d2 = sp2s[(wid * 2 + py) * 8 + px] + sw - 2.f * acc[py][px];
    float dd = sqrtf(fmaxf(d2, 1e-12f));
    float thr = wave_kth32(dd, lane);
    float th = fminf(thr, w_);
    float a = 1.f - ((dd > th) ? w_ : dd) / w_;
    pooled[px >> 1] += a * A2[py][px & 1];
  }
#pragma unroll
  for (int g = 0; g < 4; g++) {
    a1[((((size_t)(br * 16 + n)) * 48 + (gy * 4 + wid)) * 48 + (gx * 4 + g)) *
           64 + lane] = pooled[g] * 0.25f;
  }
}

// ---------------- Layers 2/3: MFMA split-bf16 RBF conv ---------------------
// 256 threads = 4 waves; block covers 4 rows x 8 cols of conv pixels.
// Each wave owns COUT/4 filters (ng = wave id) and ALL 32 pixels (mt 0/1).
// B fragments are double-buffered in registers (prefetch chunk+1 during
// chunk's MFMAs) to keep global loads in flight.
template <int CIN, int COUT, int HIN, int KRANK, int POOL, int LIDX>
__global__ __launch_bounds__(256) void mfma_rbf3(
    const float* __restrict__ in,            // [3][16][HIN][HIN][CIN]
    const unsigned short* __restrict__ bph,  // packed hi
    const unsigned short* __restrict__ bpl,  // packed lo
    const float* __restrict__ sw2v,          // [3][COUT]
    const float* __restrict__ tri,
    float* __restrict__ out) {
  constexpr int CC = CIN / 32;
  constexpr int NCH = 9 * CC;               // K chunks of 32
  constexpr int NT = COUT / 16;
  constexpr int NTW = NT / 4;               // N tiles per wave
  constexpr int PADC = COUT + 4;
  constexpr int WIN_USH = 60 * CIN;         // per buffer (h or l)
  constexpr int WIN_BYTES = 2 * WIN_USH * 2;
  constexpr int DMAT_BYTES = 32 * PADC * 4;
  constexpr int UNI_BYTES = WIN_BYTES > DMAT_BYTES ? WIN_BYTES : DMAT_BYTES;

  __shared__ __align__(16) char uni[UNI_BYTES];
  __shared__ float cellq[60][4];
  __shared__ float cellsum[60];
  __shared__ float sp2[32];
  __shared__ float thrs[32];
  __shared__ float sw2s[COUT];

  unsigned short* winh = (unsigned short*)uni;
  unsigned short* winl = winh + WIN_USH;
  float* dmat = (float*)uni;  // aliases win after conv

  const int GX = HIN / 8;
  const int gy = blockIdx.x / GX, gx = blockIdx.x % GX;
  const int n = blockIdx.y, br = blockIdx.z;
  const int t = threadIdx.x;
  const int lane = t & 63;
  const int wvid = t >> 6;
  const int ng = wvid;  // N quarter

  const float w_ = tri[br * 3 + LIDX];
  const int y0 = gy * 4 - 1, x0 = gx * 8 - 1;
  const float* ib = in + ((size_t)(br * 16 + n)) * HIN * HIN * CIN;

  // ---- stage window (fp32 -> bf16 hi/lo, swizzled) + cell partial sums ----
  for (int i = t; i < COUT; i += 256) sw2s[i] = sw2v[br * COUT + i];
  if (t < 240) {
    const int cell = t >> 2, q = t & 3;
    const int wy = cell / 10, wx = cell - (cell / 10) * 10;
    const int y = y0 + wy, xx = x0 + wx;
    const bool ok = (y >= 0 && y < HIN && xx >= 0 && xx < HIN);
    const float* rp = ib + ((size_t)y * HIN + xx) * CIN + q * (CIN / 4);
    const int sx = (wx & 7) << 3;
    float ss = 0.f;
#pragma unroll
    for (int cq = 0; cq < CIN / 16; cq++) {
      float4 v = ok ? *reinterpret_cast<const float4*>(rp + cq * 4)
                    : make_float4(0.f, 0.f, 0.f, 0.f);
      unsigned short hh[4], ll[4];
      float fv[4] = {v.x, v.y, v.z, v.w};
#pragma unroll
      for (int j = 0; j < 4; j++) {
        float f = fv[j];
        ss += f * f;
        __hip_bfloat16 h = __float2bfloat16(f);
        float hf = __bfloat162float(h);
        __hip_bfloat16 l = __float2bfloat16(f - hf);
        hh[j] = *reinterpret_cast<unsigned short*>(&h);
        ll[j] = *reinterpret_cast<unsigned short*>(&l);
      }
      int c = q * (CIN / 4) + cq * 4;
      int cst = c ^ sx;
      *reinterpret_cast<ushort4*>(&winh[cell * CIN + cst]) =
          make_ushort4(hh[0], hh[1], hh[2], hh[3]);
      *reinterpret_cast<ushort4*>(&winl[cell * CIN + cst]) =
          make_ushort4(ll[0], ll[1], ll[2], ll[3]);
    }
    cellq[cell][q] = ss;
  }
  __syncthreads();
  if (t < 60)
    cellsum[t] = cellq[t][0] + cellq[t][1] + cellq[t][2] + cellq[t][3];
  __syncthreads();
  if (t < 32) {
    int py = t >> 3, px = t & 7;
    float s = 0.f;
#pragma unroll
    for (int ky = 0; ky < 3; ky++)
#pragma unroll
      for (int kx = 0; kx < 3; kx++) s += cellsum[(py + ky) * 10 + px + kx];
    sp2[t] = s;
  }

  // ---- conv: D[pixel][filter], 3-term split bf16, reg-dbuf B pipeline ----
  const int pix0 = lane & 15;
  const int g8 = (lane >> 4) << 3;
  const int ppy = pix0 >> 3, ppx = pix0 & 7;

  f32x4 acc[2][NTW];
  f32x4 zz = {0.f, 0.f, 0.f, 0.f};
#pragma unroll
  for (int mt = 0; mt < 2; mt++)
#pragma unroll
    for (int nt = 0; nt < NTW; nt++) acc[mt][nt] = zz;

  const size_t bbase = (size_t)br * NCH;
  const int nb0 = ng * (NTW * 16) + pix0;

  bf16x8 bufA[2 * NTW], bufB[2 * NTW];

  auto loadB = [&](int chunk, bf16x8* dst) {
    const unsigned short* p0 =
        bph + ((bbase + chunk) * COUT + nb0) * 32 + g8;
    const unsigned short* p1 =
        bpl + ((bbase + chunk) * COUT + nb0) * 32 + g8;
#pragma unroll
    for (int nt = 0; nt < NTW; nt++) {
      dst[2 * nt] = *reinterpret_cast<const bf16x8*>(p0 + nt * 512);
      dst[2 * nt + 1] = *reinterpret_cast<const bf16x8*>(p1 + nt * 512);
    }
  };

  auto compute = [&](int chunk, bf16x8* b) {
    const int kpos = chunk / CC, cc = chunk - (chunk / CC) * CC;
    const int ky = kpos / 3, kx = kpos - (kpos / 3) * 3;
    const int wx = ppx + kx;
    const int sx = (wx & 7) << 3;
    const int cbase = ((cc << 5) + g8) ^ sx;
#pragma unroll
    for (int mt = 0; mt < 2; mt++) {
      const int r0 = (mt * 2 + ppy + ky) * 10 + wx;
      bf16x8 ah = *reinterpret_cast<const bf16x8*>(&winh[r0 * CIN + cbase]);
      bf16x8 al = *reinterpret_cast<const bf16x8*>(&winl[r0 * CIN + cbase]);
#pragma unroll
      for (int nt = 0; nt < NTW; nt++) {
        acc[mt][nt] = __builtin_amdgcn_mfma_f32_16x16x32_bf16(
            ah, b[2 * nt], acc[mt][nt], 0, 0, 0);
        acc[mt][nt] = __builtin_amdgcn_mfma_f32_16x16x32_bf16(
            ah, b[2 * nt + 1], acc[mt][nt], 0, 0, 0);
        acc[mt][nt] = __builtin_amdgcn_mfma_f32_16x16x32_bf16(
            al, b[2 * nt], acc[mt][nt], 0, 0, 0);
      }
    }
  };

  loadB(0, bufA);
  for (int ch = 0; ch < NCH; ch += 2) {
    loadB(ch + 1, bufB);
    compute(ch, bufA);
    if (ch + 2 < NCH) loadB(ch + 2, bufA);
    compute(ch + 1, bufB);
  }

  __syncthreads();  // conv reads of win done (alias!), sp2 visible

  // ---- d = sqrt(|p|^2 + |w|^2 - 2 dot) into dmat -------------------------
  const int rgrp = (lane >> 4) << 2;
#pragma unroll
  for (int mt = 0; mt < 2; mt++) {
    const int prow = mt * 16 + rgrp;
#pragma unroll
    for (int nt = 0; nt < NTW; nt++) {
      const int col = ng * (NTW * 16) + nt * 16 + pix0;
      const float sw = sw2s[col];
#pragma unroll
      for (int rg = 0; rg < 4; rg++) {
        const int pix = prow + rg;
        float d2 = sp2[pix] + sw - 2.f * acc[mt][nt][rg];
        dmat[pix * PADC + col] = sqrtf(fmaxf(d2, 1e-12f));
      }
    }
  }
  __syncthreads();

  // ---- per-pixel top-k threshold: radix select, 2 pixels fused for ILP ---
  for (int i = 0; i < 8; i += 2) {
    const int p0 = wvid * 8 + i, p1 = p0 + 1;
    unsigned int a0, a1v, a2, a3, b0, b1, b2, b3;
    if constexpr (COUT == 256) {
      float4 fa = *reinterpret_cast<const float4*>(&dmat[p0 * PADC + lane * 4]);
      float4 fb = *reinterpret_cast<const float4*>(&dmat[p1 * PADC + lane * 4]);
      a0 = __float_as_uint(fa.x); a1v = __float_as_uint(fa.y);
      a2 = __float_as_uint(fa.z); a3 = __float_as_uint(fa.w);
      b0 = __float_as_uint(fb.x); b1 = __float_as_uint(fb.y);
      b2 = __float_as_uint(fb.z); b3 = __float_as_uint(fb.w);
    } else {
      float2 fa = *reinterpret_cast<const float2*>(&dmat[p0 * PADC + lane * 2]);
      float2 fb = *reinterpret_cast<const float2*>(&dmat[p1 * PADC + lane * 2]);
      a0 = __float_as_uint(fa.x); a1v = __float_as_uint(fa.y);
      b0 = __float_as_uint(fb.x); b1 = __float_as_uint(fb.y);
      a2 = a3 = b2 = b3 = 0;
    }
    unsigned int pre0 = 0, pre1 = 0;
    int rem0 = KRANK, rem1 = KRANK;
    for (int b = 30; b >= 0; --b) {
      unsigned int top0 = (pre0 >> b) | 1u;
      unsigned int top1 = (pre1 >> b) | 1u;
      int c0 = __popcll(__ballot((a0 >> b) == top0)) +
               __popcll(__ballot((a1v >> b) == top0));
      int c1 = __popcll(__ballot((b0 >> b) == top1)) +
               __popcll(__ballot((b1 >> b) == top1));
      if constexpr (COUT == 256) {
        c0 += __popcll(__ballot((a2 >> b) == top0)) +
              __popcll(__ballot((a3 >> b) == top0));
        c1 += __popcll(__ballot((b2 >> b) == top1)) +
              __popcll(__ballot((b3 >> b) == top1));
      }
      if (c0 > rem0) pre0 |= (1u << b); else rem0 -= c0;
      if (c1 > rem1) pre1 |= (1u << b); else rem1 -= c1;
    }
    if (lane == 0) {
      thrs[p0] = __uint_as_float(pre0);
      thrs[p1] = __uint_as_float(pre1);
    }
  }
  __syncthreads();

  // ---- activation (+ pool) + store ---------------------------------------
  if (POOL) {
    const int GW = HIN / 2;
    float* ob = out + ((size_t)(br * 16 + n)) * GW * GW * COUT;
    for (int i = t; i < 8 * COUT; i += 256) {
      int q = i / COUT;
      int ch = i - q * COUT;
      int qy = q >> 2, qx = q & 3;
      int p00 = qy * 16 + qx * 2;
      float d00 = dmat[p00 * PADC + ch];
      float d01 = dmat[(p00 + 1) * PADC + ch];
      float d10 = dmat[(p00 + 8) * PADC + ch];
      float d11 = dmat[(p00 + 9) * PADC + ch];
      float t00 = fminf(thrs[p00], w_);
      float t01 = fminf(thrs[p00 + 1], w_);
      float t10 = fminf(thrs[p00 + 8], w_);
      float t11 = fminf(thrs[p00 + 9], w_);
      float a00 = 1.f - ((d00 > t00) ? w_ : d00) / w_;
      float a01 = 1.f - ((d01 > t01) ? w_ : d01) / w_;
      float a10 = 1.f - ((d10 > t10) ? w_ : d10) / w_;
      float a11 = 1.f - ((d11 > t11) ? w_ : d11) / w_;
      float po =
          0.25f * (a00 * 0.9f + a01 * 0.93f + a10 * 0.96f + a11 * 0.99f);
      ob[((size_t)((gy * 2 + qy) * GW + gx * 4 + qx)) * COUT + ch] = po;
    }
  } else {
    float* ob = out + ((size_t)(br * 16 + n)) * HIN * HIN * COUT;
    for (int i = 0; i < 8; i++) {
      int r = wvid * 8 + i;
      float4 dv = *reinterpret_cast<const float4*>(&dmat[r * PADC + lane * 4]);
      float th = fminf(thrs[r], w_);
      float4 av;
      av.x = 1.f - ((dv.x > th) ? w_ : dv.x) / w_;
      av.y = 1.f - ((dv.y > th) ? w_ : dv.y) / w_;
      av.z = 1.f - ((dv.z > th) ? w_ : dv.z) / w_;
      av.w = 1.f - ((dv.w > th) ? w_ : dv.w) / w_;
      int oy = gy * 4 + (r >> 3), ox = gx * 8 + (r & 7);
      *reinterpret_cast<float4*>(
          &ob[((size_t)(oy * HIN + ox)) * COUT + lane * 4]) = av;
    }
  }
}

// ---------------- FC: split-K partials + reduce ----------------------------
__global__ __launch_bounds__(256) void fc_partial_kernel(
    const float* __restrict__ feats, const float* __restrict__ fcwt,
    float* __restrict__ partial) {
  const int oo = blockIdx.x;  // 0..9
  const int n = blockIdx.y;   // 0..15
  const int s = blockIdx.z;   // 0..7
  const int t = threadIdx.x;
  const int i0 = s * 4608;
  float acc = 0.f;
  for (int br = 0; br < 3; br++) {
    const float4* fb = reinterpret_cast<const float4*>(
        feats + ((size_t)(br * 16 + n)) * 147456);
    const float4* wb = reinterpret_cast<const float4*>(
        fcwt + ((size_t)(oo * 3 + br)) * 147456);
    for (int i = i0 + t; i < i0 + 4608; i += 256) {
      float4 f = fb[i], w = wb[i];
      acc += f.x * w.x + f.y * w.y + f.z * w.z + f.w * w.w;
    }
  }
  __shared__ float red[256];
  red[t] = acc;
  __syncthreads();
  for (int st = 128; st > 0; st >>= 1) {
    if (t < st) red[t] += red[t + st];
    __syncthreads();
  }
  if (t == 0) partial[((size_t)oo * 16 + n) * 8 + s] = red[0];
}

__global__ __launch_bounds__(256) void fc_final_kernel(
    const float* __restrict__ partial, const float* __restrict__ fcb,
    float* __restrict__ outp) {
  const int t = threadIdx.x;
  if (t < 160) {
    int oo = t / 16, n = t % 16;
    float s = 0.f;
#pragma unroll
    for (int q = 0; q < 8; q++) s += partial[((size_t)oo * 16 + n) * 8 + q];
    outp[n * 10 + oo] = s + fcb[oo];
  }
}

// ---------------------------------------------------------------------------
extern "C" void kernel_launch(void* const* d_in, const int* in_sizes, int n_in,
                              void* d_out, int out_size, void* d_ws,
                              size_t ws_size, hipStream_t stream) {
  const float* x   = (const float*)d_in[0];
  const float* w1  = (const float*)d_in[1];
  const float* w2  = (const float*)d_in[2];
  const float* w3  = (const float*)d_in[3];
  const float* tri = (const float*)d_in[4];
  const float* fcw = (const float*)d_in[5];
  const float* fcb = (const float*)d_in[6];
  float* out = (float*)d_out;

  float* ws = (float*)d_ws;
  float* a1    = ws;                  // 7,077,888
  float* a2    = a1 + 7077888;        // 3,538,944
  float* feats = a2 + 3538944;        // 7,077,888
  float* s1    = feats + 7077888;     // 192
  float* s2    = s1 + 192;            // 384
  float* s3    = s2 + 384;            // 768
  float* w1t   = s3 + 768;            // 4,800
  unsigned short* bph2 = (unsigned short*)(w1t + 4800);  // 221,184 ushorts
  unsigned short* bpl2 = bph2 + 221184;
  unsigned short* bph3 = bpl2 + 221184;                  // 884,736
  unsigned short* bpl3 = bph3 + 884736;
  float* partial = (float*)(bpl3 + 884736);              // 1,280 floats
  float* fcwt = a1;  // aliases a1 (dead after layer2)

  tr_w_kernel<<<dim3(19), dim3(256), 0, stream>>>(w1, w1t, 64, 25);
  sw2_kernel<<<dim3(6), dim3(256), 0, stream>>>(w1, w2, w3, s1, s2, s3);
  pack_w_kernel<64, 128><<<dim3(128, 1, 3), dim3(256), 0, stream>>>(w2, bph2,
                                                                    bpl2);
  pack_w_kernel<128, 256><<<dim3(256, 1, 3), dim3(256), 0, stream>>>(w3, bph3,
                                                                     bpl3);

  layer1_kernel<<<dim3(144, 16, 3), dim3(256), 0, stream>>>(x, w1t, s1, tri,
                                                            a1);
  mfma_rbf3<64, 128, 48, 63, 1, 1>
      <<<dim3(72, 16, 3), dim3(256), 0, stream>>>(a1, bph2, bpl2, s2, tri, a2);
  // a1 dead; reuse for transposed fc weights
  tr_fcw_kernel<<<dim3(144, 30), dim3(32, 8), 0, stream>>>(fcw, fcwt);
  mfma_rbf3<128, 256, 24, 152, 0, 2>
      <<<dim3(18, 16, 3), dim3(256), 0, stream>>>(a2, bph3, bpl3, s3, tri,
                                                  feats);
  fc_partial_kernel<<<dim3(10, 16, 8), dim3(256), 0, stream>>>(feats, fcwt,
                                                               partial);
  fc_final_kernel<<<dim3(1), dim3(256), 0, stream>>>(partial, fcb, out);
}